// Round 15
// baseline (566.320 us; speedup 1.0000x reference)
//
#include <hip/hip_runtime.h>
#include <stdint.h>

#define NTOK 65536          // B*T
#define DE 384
#define QSTR 1280           // padded qkv row stride (1152 used)

typedef __bf16 bf16x8 __attribute__((ext_vector_type(8)));
typedef float  f32x4  __attribute__((ext_vector_type(4)));
typedef float  f32x16 __attribute__((ext_vector_type(16)));
typedef unsigned short u16x8 __attribute__((ext_vector_type(8)));

__device__ __forceinline__ unsigned short f2bf(float f) {
  union { float fl; unsigned u; } a; a.fl = f;
  unsigned r = a.u + 0x7fffu + ((a.u >> 16) & 1u);
  return (unsigned short)(r >> 16);
}
__device__ __forceinline__ float b2f(unsigned short s) {
  union { unsigned u; float f; } v; v.u = (unsigned)s << 16; return v.f;
}

__device__ __forceinline__ void gll16(const void* g, void* l) {
  __builtin_amdgcn_global_load_lds((const __attribute__((address_space(1))) void*)g,
                                   (__attribute__((address_space(3))) void*)l, 16, 0, 0);
}

__device__ __forceinline__ bf16x8 ds128(unsigned addr) {
  bf16x8 r;
  asm volatile("ds_read_b128 %0, %1" : "=v"(r) : "v"(addr));
  return r;
}

// ---------------- weight packing ----------------
__global__ void pack_t(unsigned short* __restrict__ dst, const float* __restrict__ src,
                       int R, int C) {
  int t = blockIdx.x * 256 + threadIdx.x;
  if (t >= R * C) return;
  int r = t / C, c = t - r * C;
  dst[(size_t)c * R + r] = f2bf(src[t]);
}

// Wqkv_t padded [1280][384]: n = which*384 + h*64 + e  (rows >=1152 are zero)
__global__ void qkv_pack(const float* __restrict__ wq, const float* __restrict__ wk,
                         const float* __restrict__ wv, unsigned short* __restrict__ dst) {
  int t = blockIdx.x * 256 + threadIdx.x;
  if (t >= QSTR * 384) return;
  int n = t / 384, k = t - n * 384;
  unsigned short v = 0;
  if (n < 1152) {
    int which = n / 384, r = n - which * 384;
    const float* src = which == 0 ? wq : (which == 1 ? wk : wv);
    int h = r >> 6, e = r & 63;
    v = f2bf(src[h * 24576 + k * 64 + e]);
  }
  dst[t] = v;
}

// ---------------- layernorm f32-in -> bf16-out, wave per row ----------------
__global__ __launch_bounds__(256) void ln_kernel(const float* __restrict__ x,
                                                 const float* __restrict__ g,
                                                 const float* __restrict__ be,
                                                 unsigned short* __restrict__ out) {
  int wave = threadIdx.x >> 6, lane = threadIdx.x & 63;
  size_t row = (size_t)blockIdx.x * 4 + wave;
  const float* xr = x + row * DE;
  int c0 = lane * 2;
  float2 v0 = *(const float2*)(xr + c0);
  float2 v1 = *(const float2*)(xr + 128 + c0);
  float2 v2 = *(const float2*)(xr + 256 + c0);
  float s  = v0.x + v0.y + v1.x + v1.y + v2.x + v2.y;
  float ss = v0.x*v0.x + v0.y*v0.y + v1.x*v1.x + v1.y*v1.y + v2.x*v2.x + v2.y*v2.y;
#pragma unroll
  for (int m = 1; m < 64; m <<= 1) { s += __shfl_xor(s, m); ss += __shfl_xor(ss, m); }
  float mu = s * (1.0f / 384.0f);
  float rstd = rsqrtf(ss * (1.0f / 384.0f) - mu * mu + 1e-5f);
  unsigned short* orow = out + row * DE;
  {
    float a0 = (v0.x - mu) * rstd * g[c0] + be[c0];
    float a1 = (v0.y - mu) * rstd * g[c0 + 1] + be[c0 + 1];
    *(unsigned*)(orow + c0) = (unsigned)f2bf(a0) | ((unsigned)f2bf(a1) << 16);
  }
  {
    int c = c0 + 128;
    float a0 = (v1.x - mu) * rstd * g[c] + be[c];
    float a1 = (v1.y - mu) * rstd * g[c + 1] + be[c + 1];
    *(unsigned*)(orow + c) = (unsigned)f2bf(a0) | ((unsigned)f2bf(a1) << 16);
  }
  {
    int c = c0 + 256;
    float a0 = (v2.x - mu) * rstd * g[c] + be[c];
    float a1 = (v2.y - mu) * rstd * g[c + 1] + be[c + 1];
    *(unsigned*)(orow + c) = (unsigned)f2bf(a0) | ((unsigned)f2bf(a1) << 16);
  }
}

// ---------------- GEMM core, 32x32x16 MFMA (R11-verified) ----------------
template<int EPI, int BM, int BN, int WM, int WN>
__device__ __forceinline__
void gemm_core(const unsigned short* __restrict__ A, const unsigned short* __restrict__ Bt,
               int M, int K, int Nst, int stride, int ntx,
               const float* __restrict__ bias, const unsigned short* __restrict__ residb,
               float* __restrict__ outf, unsigned short* __restrict__ outb) {
  constexpr int T = WM * WN * 64;
  constexpr int MWT = BM / WM, NWT = BN / WN;
  constexpr int MT = MWT / 32, NT = NWT / 32;
  constexpr int LA = (BM * 128) / (T * 16);
  constexpr int LB = (BN * 128) / (T * 16);
  __shared__ __align__(16) unsigned short As[2][BM * 64];
  __shared__ __align__(16) unsigned short Bs[2][BN * 64];
  const int tid = threadIdx.x;
  const int wave = tid >> 6, lane = tid & 63;

  const int nwg = gridDim.x;
  const int cpx = nwg >> 3;
  const int wg = (blockIdx.x & 7) * cpx + (blockIdx.x >> 3);
  const int bx = wg % ntx, by = wg / ntx;
  const int mBase = by * BM, nBase = bx * BN;
  const int wm = (wave / WN) * MWT, wn = (wave % WN) * NWT;
  const int cr = lane & 31;
  const int hg = lane >> 5;

  const unsigned asb = (unsigned)(uintptr_t)&As[0][0];
  const unsigned bsb = (unsigned)(uintptr_t)&Bs[0][0];

  f32x16 acc[MT][NT];
#pragma unroll
  for (int i = 0; i < MT; ++i)
#pragma unroll
    for (int j = 0; j < NT; ++j)
#pragma unroll
      for (int r = 0; r < 16; ++r) acc[i][j][r] = 0.f;

  auto stage = [&](int buf, int kt) {
#pragma unroll
    for (int i = 0; i < LA; ++i) {
      int Lb = i * (T * 16) + wave * 1024;
      int L = Lb + lane * 16;
      int row = L >> 7;
      int col = ((((L >> 4) & 7) ^ (row & 7) ^ ((row >> 3) & 3)) << 3);
      gll16(A + (size_t)(mBase + row) * K + kt + col, (unsigned short*)As[buf] + (Lb >> 1));
    }
#pragma unroll
    for (int i = 0; i < LB; ++i) {
      int Lb = i * (T * 16) + wave * 1024;
      int L = Lb + lane * 16;
      int row = L >> 7;
      int col = ((((L >> 4) & 7) ^ (row & 7) ^ ((row >> 3) & 3)) << 3);
      gll16(Bt + (size_t)(nBase + row) * K + kt + col, (unsigned short*)Bs[buf] + (Lb >> 1));
    }
  };

  const int NK = K >> 6;
  stage(0, 0);
  for (int t = 0; t < NK; ++t) {
    const int cur = t & 1;
    if (t + 1 < NK) {
      stage(cur ^ 1, (t + 1) << 6);
      if constexpr (LA + LB == 8)      asm volatile("s_waitcnt vmcnt(8)" ::: "memory");
      else if constexpr (LA + LB == 7) asm volatile("s_waitcnt vmcnt(7)" ::: "memory");
      else                             asm volatile("s_waitcnt vmcnt(6)" ::: "memory");
    } else {
      asm volatile("s_waitcnt vmcnt(0)" ::: "memory");
    }
    asm volatile("" ::: "memory");
    __builtin_amdgcn_s_barrier();
    asm volatile("" ::: "memory");

    const unsigned ab = asb + (cur ? (unsigned)(BM * 128) : 0u);
    const unsigned bb = bsb + (cur ? (unsigned)(BN * 128) : 0u);
#pragma unroll
    for (int k2 = 0; k2 < 2; ++k2) {
      bf16x8 bfr[2][NT], af[2][MT];
#pragma unroll
      for (int kk = 0; kk < 2; ++kk) {
        const int ks = k2 * 2 + kk;
#pragma unroll
        for (int nt = 0; nt < NT; ++nt) {
          int row = wn + nt * 32 + cr;
          unsigned slot = (unsigned)(((ks * 2 + hg) ^ (row & 7) ^ ((row >> 3) & 3)) & 7);
          bfr[kk][nt] = ds128(bb + (unsigned)(row << 7) + (slot << 4));
        }
#pragma unroll
        for (int mt = 0; mt < MT; ++mt) {
          int row = wm + mt * 32 + cr;
          unsigned slot = (unsigned)(((ks * 2 + hg) ^ (row & 7) ^ ((row >> 3) & 3)) & 7);
          af[kk][mt] = ds128(ab + (unsigned)(row << 7) + (slot << 4));
        }
      }
      asm volatile("s_waitcnt lgkmcnt(0)" ::: "memory");
      __builtin_amdgcn_sched_barrier(0);
      __builtin_amdgcn_s_setprio(1);
#pragma unroll
      for (int kk = 0; kk < 2; ++kk)
#pragma unroll
        for (int mt = 0; mt < MT; ++mt)
#pragma unroll
          for (int nt = 0; nt < NT; ++nt)
            acc[mt][nt] = __builtin_amdgcn_mfma_f32_32x32x16_bf16(af[kk][mt], bfr[kk][nt],
                                                                  acc[mt][nt], 0, 0, 0);
      __builtin_amdgcn_s_setprio(0);
    }
    asm volatile("" ::: "memory");
    __builtin_amdgcn_s_barrier();
    asm volatile("" ::: "memory");
  }

#pragma unroll
  for (int mt = 0; mt < MT; ++mt) {
#pragma unroll
    for (int nt = 0; nt < NT; ++nt) {
      const int gn = nBase + wn + nt * 32 + cr;
      if (gn < Nst) {
#pragma unroll
        for (int r = 0; r < 16; ++r) {
          const int gm = mBase + wm + mt * 32 + (r & 3) + ((r >> 2) << 3) + (hg << 2);
          float val = acc[mt][nt][r];
          size_t idx = (size_t)gm * stride + gn;
          if (EPI == 0) {
            outb[idx] = f2bf(val);
          } else if (EPI == 2) {
            float rr = val + bias[gn];
            outb[idx] = f2bf(rr > 0.f ? rr : 0.f);
          } else {
            outf[idx] = val + bias[gn] + b2f(residb[idx]);
          }
        }
      }
    }
  }
}

__global__ __launch_bounds__(512, 1)
void gemm_qkv(const unsigned short* __restrict__ A, const unsigned short* __restrict__ Bt,
              int M, int K, int Nst, int stride, int ntx, const float* __restrict__ bias,
              const unsigned short* __restrict__ residb, float* __restrict__ outf,
              unsigned short* __restrict__ outb) {
  gemm_core<0, 256, 192, 4, 2>(A, Bt, M, K, Nst, stride, ntx, bias, residb, outf, outb);
}
__global__ __launch_bounds__(512, 1)
void gemm_mlp1(const unsigned short* __restrict__ A, const unsigned short* __restrict__ Bt,
               int M, int K, int Nst, int stride, int ntx, const float* __restrict__ bias,
               const unsigned short* __restrict__ residb, float* __restrict__ outf,
               unsigned short* __restrict__ outb) {
  gemm_core<2, 256, 256, 2, 4>(A, Bt, M, K, Nst, stride, ntx, bias, residb, outf, outb);
}
__global__ __launch_bounds__(512, 1)
void gemm_mlp2(const unsigned short* __restrict__ A, const unsigned short* __restrict__ Bt,
               int M, int K, int Nst, int stride, int ntx, const float* __restrict__ bias,
               const unsigned short* __restrict__ residb, float* __restrict__ outf,
               unsigned short* __restrict__ outb) {
  gemm_core<3, 256, 128, 4, 2>(A, Bt, M, K, Nst, stride, ntx, bias, residb, outf, outb);
}

// ======== fused attention + proj + LN2: one block per 128 tokens ========
// Attention (6 heads, 8 waves x 16 q-rows, single-pass softmax) writes output
// into AO LDS [48 k-slots][128 rows] (slot stride 2064B). Proj reads A frags
// from AO (ds_read group = row mod 8 -> conflict-free), stages wproj tiles via
// gll16 (single-buffer, BK=64, two-term swizzle), then fused LN2 epilogue.
__global__ __launch_bounds__(512)
void attnproj(const unsigned short* __restrict__ qkvn, const unsigned short* __restrict__ wprjt,
              const float* __restrict__ bproj, const float* __restrict__ x,
              const float* __restrict__ g2, const float* __restrict__ be2,
              unsigned short* __restrict__ x1b, unsigned short* __restrict__ hbuf) {
  __shared__ __align__(16) unsigned short AO[48 * 1032];   // 99072 B, slot stride 1032 ushorts
  __shared__ __align__(16) unsigned short SCR[24576];      // 49152 B: {Vt 16384 + Pw 4096} | Bs 24576
  __shared__ float red[128][4][2];

  const int tid = threadIdx.x;
  const int wave = tid >> 6, lane = tid & 63;
  const int wg = blockIdx.x;                       // 512 blocks
  const size_t tok0 = (size_t)wg << 7;
  const unsigned short* base = qkvn + (size_t)(wg >> 1) * 256 * QSTR;
  const int q0 = (wg & 1) << 7;

  unsigned short* Vt = SCR;
  unsigned short* Pww = SCR + 16384 + wave * 512;  // 16x32 per wave
  const unsigned aob = (unsigned)(uintptr_t)&AO[0];
  const unsigned bsb = (unsigned)(uintptr_t)&SCR[0];

  const int fr = lane & 15, fg = lane >> 4, fk = fg << 3;
  const float scale = 0.051031036307982884f;       // 1/sqrt(384)
  const f32x4 z = {0.f, 0.f, 0.f, 0.f};

  // ---------- attention phase ----------
  for (int h = 0; h < 6; ++h) {
    const unsigned short* qb  = base + h * 64;
    const unsigned short* kbp = base + 384 + h * 64;
    const unsigned short* vbp = base + 768 + h * 64;
    // stage V^T (same swizzle as verified attn kernel), 512 threads
    {
      int s = tid & 255, half = tid >> 8;
      u16x8 v8[4];
#pragma unroll
      for (int j = 0; j < 4; ++j)
        v8[j] = *(const u16x8*)(vbp + (size_t)s * QSTR + half * 32 + j * 8);
#pragma unroll
      for (int e2 = 0; e2 < 32; ++e2) {
        int e = half * 32 + e2;
        Vt[(e << 8) + (s ^ ((e & 7) << 3))] = v8[e2 >> 3][e2 & 7];
      }
    }
    __syncthreads();

    bf16x8 qf0 = *(const bf16x8*)(qb + (size_t)(q0 + wave * 16 + fr) * QSTR + fk);
    bf16x8 qf1 = *(const bf16x8*)(qb + (size_t)(q0 + wave * 16 + fr) * QSTR + 32 + fk);

    f32x4 oacc[4];
    float psum[4];
#pragma unroll
    for (int nb = 0; nb < 4; ++nb) oacc[nb] = z;
#pragma unroll
    for (int i = 0; i < 4; ++i) psum[i] = 0.f;

    for (int kb2 = 0; kb2 < 8; ++kb2) {
#pragma unroll
      for (int c2 = 0; c2 < 2; ++c2) {
        int cb = kb2 * 2 + c2;
        bf16x8 kf0 = *(const bf16x8*)(kbp + (size_t)(cb * 16 + fr) * QSTR + fk);
        bf16x8 kf1 = *(const bf16x8*)(kbp + (size_t)(cb * 16 + fr) * QSTR + 32 + fk);
        f32x4 s = __builtin_amdgcn_mfma_f32_16x16x32_bf16(qf0, kf0, z, 0, 0, 0);
        s = __builtin_amdgcn_mfma_f32_16x16x32_bf16(qf1, kf1, s, 0, 0, 0);
#pragma unroll
        for (int i = 0; i < 4; ++i) {
          float p = __expf(fminf(scale * s[i], 60.f));
          psum[i] += p;
          Pww[((fg << 2) + i) * 32 + c2 * 16 + fr] = f2bf(p);
        }
      }
      bf16x8 pa = *(const bf16x8*)(Pww + fr * 32 + fk);
      bf16x8 vf[4];
#pragma unroll
      for (int nb = 0; nb < 4; ++nb) {
        int e = nb * 16 + fr;
        vf[nb] = *(const bf16x8*)(&Vt[(e << 8) + ((kb2 * 32 + fk) ^ ((e & 7) << 3))]);
      }
#pragma unroll
      for (int nb = 0; nb < 4; ++nb)
        oacc[nb] = __builtin_amdgcn_mfma_f32_16x16x32_bf16(pa, vf[nb], oacc[nb], 0, 0, 0);
    }

    float rs[4];
#pragma unroll
    for (int i = 0; i < 4; ++i) {
      float v = psum[i];
      v += __shfl_xor(v, 1);
      v += __shfl_xor(v, 2);
      v += __shfl_xor(v, 4);
      v += __shfl_xor(v, 8);
      rs[i] = 1.0f / v;
    }

    // write AO[slot = c>>3][row = tr], elem c&7
#pragma unroll
    for (int nb = 0; nb < 4; ++nb) {
#pragma unroll
      for (int i = 0; i < 4; ++i) {
        int tr = wave * 16 + (fg << 2) + i;
        int c = h * 64 + nb * 16 + fr;
        AO[(c >> 3) * 1032 + tr * 8 + (c & 7)] = f2bf(oacc[nb][i] * rs[i]);
      }
    }
    __syncthreads();   // Vt restage / AO visibility
  }

  // ---------- proj + LN2 phase ----------
  const int cr = lane & 31, hg = lane >> 5;
  const int wm = (wave >> 2) << 6;     // 0 / 64
  const int wni = wave & 3;
  const int wn = wni * 96;

  f32x16 acc[2][3];
#pragma unroll
  for (int mt = 0; mt < 2; ++mt)
#pragma unroll
    for (int nt = 0; nt < 3; ++nt)
#pragma unroll
      for (int r = 0; r < 16; ++r) acc[mt][nt][r] = 0.f;

  for (int t = 0; t < 6; ++t) {
    // stage Bs: 384 rows x 64 cols, two-term swizzle, 6 rounds of 8KB
#pragma unroll
    for (int i = 0; i < 6; ++i) {
      int Lb = i * 8192 + wave * 1024;
      int L = Lb + lane * 16;
      int row = L >> 7;
      int col = ((((L >> 4) & 7) ^ (row & 7) ^ ((row >> 3) & 3)) << 3);
      gll16(wprjt + (size_t)row * 384 + t * 64 + col, SCR + (Lb >> 1));
    }
    asm volatile("s_waitcnt vmcnt(0)" ::: "memory");
    __builtin_amdgcn_s_barrier();
    asm volatile("" ::: "memory");

#pragma unroll
    for (int k2 = 0; k2 < 2; ++k2) {
      bf16x8 bfr[2][3], af[2][2];
#pragma unroll
      for (int kk = 0; kk < 2; ++kk) {
        const int sl = (k2 * 2 + kk) * 2 + hg;    // 0..7 within tile
#pragma unroll
        for (int nt = 0; nt < 3; ++nt) {
          int row = wn + nt * 32 + cr;
          unsigned slot = (unsigned)((sl ^ (row & 7) ^ ((row >> 3) & 3)) & 7);
          bfr[kk][nt] = ds128(bsb + (unsigned)(row << 7) + (slot << 4));
        }
        const int sa = t * 8 + sl;                 // absolute k-slot 0..47
#pragma unroll
        for (int mt = 0; mt < 2; ++mt) {
          int row = wm + mt * 32 + cr;
          af[kk][mt] = ds128(aob + (unsigned)sa * 2064u + (unsigned)(row << 4));
        }
      }
      asm volatile("s_waitcnt lgkmcnt(0)" ::: "memory");
      __builtin_amdgcn_sched_barrier(0);
      __builtin_amdgcn_s_setprio(1);
#pragma unroll
      for (int kk = 0; kk < 2; ++kk)
#pragma unroll
        for (int mt = 0; mt < 2; ++mt)
#pragma unroll
          for (int nt = 0; nt < 3; ++nt)
            acc[mt][nt] = __builtin_amdgcn_mfma_f32_32x32x16_bf16(af[kk][mt], bfr[kk][nt],
                                                                  acc[mt][nt], 0, 0, 0);
      __builtin_amdgcn_s_setprio(0);
    }
    asm volatile("" ::: "memory");
    __builtin_amdgcn_s_barrier();   // done reading Bs before restage
    asm volatile("" ::: "memory");
  }

  // epilogue: x1 = acc + bias + x (f32 resid); row-LN over 384; dual store
#pragma unroll
  for (int mt = 0; mt < 2; ++mt)
#pragma unroll
    for (int nt = 0; nt < 3; ++nt) {
      const int gn = wn + nt * 32 + cr;
#pragma unroll
      for (int r = 0; r < 16; ++r) {
        const int lr = wm + mt * 32 + (r & 3) + ((r >> 2) << 3) + (hg << 2);
        size_t idx = (tok0 + lr) * DE + gn;
        acc[mt][nt][r] = acc[mt][nt][r] + bproj[gn] + x[idx];
      }
    }
#pragma unroll
  for (int mt = 0; mt < 2; ++mt)
#pragma unroll
    for (int r = 0; r < 16; ++r) {
      float s = 0.f, ss = 0.f;
#pragma unroll
      for (int nt = 0; nt < 3; ++nt) {
        float v = acc[mt][nt][r];
        s += v; ss += v * v;
      }
      s += __shfl_xor(s, 1);  ss += __shfl_xor(ss, 1);
      s += __shfl_xor(s, 2);  ss += __shfl_xor(ss, 2);
      s += __shfl_xor(s, 4);  ss += __shfl_xor(ss, 4);
      s += __shfl_xor(s, 8);  ss += __shfl_xor(ss, 8);
      s += __shfl_xor(s, 16); ss += __shfl_xor(ss, 16);
      if (cr == 0) {
        int row = wm + mt * 32 + (r & 3) + ((r >> 2) << 3) + (hg << 2);
        red[row][wni][0] = s;
        red[row][wni][1] = ss;
      }
    }
  __syncthreads();
#pragma unroll
  for (int mt = 0; mt < 2; ++mt)
#pragma unroll
    for (int r = 0; r < 16; ++r) {
      int row = wm + mt * 32 + (r & 3) + ((r >> 2) << 3) + (hg << 2);
      float s = red[row][0][0] + red[row][1][0] + red[row][2][0] + red[row][3][0];
      float ss = red[row][0][1] + red[row][1][1] + red[row][2][1] + red[row][3][1];
      float mu = s * (1.0f / 384.0f);
      float rstd = rsqrtf(ss * (1.0f / 384.0f) - mu * mu + 1e-5f);
#pragma unroll
      for (int nt = 0; nt < 3; ++nt) {
        const int gn = wn + nt * 32 + cr;
        size_t idx = (tok0 + row) * DE + gn;
        float x1v = acc[mt][nt][r];
        x1b[idx] = f2bf(x1v);
        hbuf[idx] = f2bf((x1v - mu) * rstd * g2[gn] + be2[gn]);
      }
    }
}

// ---------------- launch ----------------
extern "C" void kernel_launch(void* const* d_in, const int* in_sizes, int n_in,
                              void* d_out, int out_size, void* d_ws, size_t ws_size,
                              hipStream_t stream) {
  const float* x     = (const float*)d_in[0];
  const float* wq    = (const float*)d_in[1];
  const float* wk    = (const float*)d_in[2];
  const float* wv    = (const float*)d_in[3];
  const float* wproj = (const float*)d_in[4];
  const float* bproj = (const float*)d_in[5];
  const float* w1    = (const float*)d_in[6];
  const float* b1    = (const float*)d_in[7];
  const float* w2    = (const float*)d_in[8];
  const float* b2    = (const float*)d_in[9];
  const float* g1    = (const float*)d_in[10];
  const float* be1   = (const float*)d_in[11];
  const float* g2    = (const float*)d_in[12];
  const float* be2   = (const float*)d_in[13];

  char* ws = (char*)d_ws;
  // layout (no aliasing of live buffers):
  //  xln  @0          (50MB, dead after qkv); x1b @0 (attnproj out, live->mlp2)
  //  qkvn @50331648   (168MB, dead after attnproj)
  //  act  @50331648   (201MB, mlp1 out over dead qkvn) ends 251658240
  //  hbuf @251658240  (50MB, attnproj LN2 out) ends 301989888
  //  weights @301989888 (~2.4MB)
  unsigned short* xln   = (unsigned short*)(ws + 0);
  unsigned short* x1b   = (unsigned short*)(ws + 0);
  unsigned short* qkvn  = (unsigned short*)(ws + 50331648);
  unsigned short* act   = (unsigned short*)(ws + 50331648);
  unsigned short* hbuf  = (unsigned short*)(ws + 251658240);
  unsigned short* wqkvt = (unsigned short*)(ws + 301989888);                       // 983040 B
  unsigned short* wprjt = (unsigned short*)(ws + 301989888 + 983040);              // 294912 B
  unsigned short* w1t   = (unsigned short*)(ws + 301989888 + 983040 + 294912);     // 1179648 B
  unsigned short* w2t   = (unsigned short*)(ws + 301989888 + 983040 + 294912 + 1179648);

  qkv_pack<<<(QSTR * 384 + 255) / 256, 256, 0, stream>>>(wq, wk, wv, wqkvt);
  pack_t<<<(147456 + 255) / 256, 256, 0, stream>>>(wprjt, wproj, 384, 384);
  pack_t<<<(589824 + 255) / 256, 256, 0, stream>>>(w1t, w1, 384, 1536);
  pack_t<<<(589824 + 255) / 256, 256, 0, stream>>>(w2t, w2, 1536, 384);

  ln_kernel<<<NTOK / 4, 256, 0, stream>>>(x, g1, be1, xln);

  // qkv: N computed = 1152 exactly (BN=192, ntx=6), storage stride 1280
  gemm_qkv<<<6 * 256, 512, 0, stream>>>(xln, wqkvt, NTOK, 384, 1152, 1280, 6,
                                        nullptr, nullptr, nullptr, qkvn);

  // fused attention + proj + LN2: one block per 128 tokens
  attnproj<<<512, 512, 0, stream>>>(qkvn, wprjt, bproj, x, g2, be2, x1b, hbuf);

  gemm_mlp1<<<6 * 256, 512, 0, stream>>>(hbuf, w1t, NTOK, 384, 1536, 1536, 6,
                                         b1, nullptr, nullptr, act);

  gemm_mlp2<<<3 * 256, 512, 0, stream>>>(act, w2t, NTOK, 1536, 384, 384, 3,
                                         b2, x1b, (float*)d_out, nullptr);
}

// Round 16
// 516.607 us; speedup vs baseline: 1.0962x; 1.0962x over previous
//
#include <hip/hip_runtime.h>
#include <stdint.h>

#define NTOK 65536          // B*T
#define DE 384
#define QSTR 1280           // padded qkv row stride (1152 used)

typedef __bf16 bf16x8 __attribute__((ext_vector_type(8)));
typedef float  f32x4  __attribute__((ext_vector_type(4)));
typedef float  f32x16 __attribute__((ext_vector_type(16)));
typedef unsigned short u16x8 __attribute__((ext_vector_type(8)));

__device__ __forceinline__ unsigned short f2bf(float f) {
  union { float fl; unsigned u; } a; a.fl = f;
  unsigned r = a.u + 0x7fffu + ((a.u >> 16) & 1u);
  return (unsigned short)(r >> 16);
}
__device__ __forceinline__ float b2f(unsigned short s) {
  union { unsigned u; float f; } v; v.u = (unsigned)s << 16; return v.f;
}

__device__ __forceinline__ void gll16(const void* g, void* l) {
  __builtin_amdgcn_global_load_lds((const __attribute__((address_space(1))) void*)g,
                                   (__attribute__((address_space(3))) void*)l, 16, 0, 0);
}

__device__ __forceinline__ bf16x8 ds128(unsigned addr) {
  bf16x8 r;
  asm volatile("ds_read_b128 %0, %1" : "=v"(r) : "v"(addr));
  return r;
}

// ---------------- weight packing ----------------
__global__ void pack_t(unsigned short* __restrict__ dst, const float* __restrict__ src,
                       int R, int C) {
  int t = blockIdx.x * 256 + threadIdx.x;
  if (t >= R * C) return;
  int r = t / C, c = t - r * C;
  dst[(size_t)c * R + r] = f2bf(src[t]);
}

// Wqkv_t padded [1280][384]: n = which*384 + h*64 + e  (rows >=1152 are zero)
__global__ void qkv_pack(const float* __restrict__ wq, const float* __restrict__ wk,
                         const float* __restrict__ wv, unsigned short* __restrict__ dst) {
  int t = blockIdx.x * 256 + threadIdx.x;
  if (t >= QSTR * 384) return;
  int n = t / 384, k = t - n * 384;
  unsigned short v = 0;
  if (n < 1152) {
    int which = n / 384, r = n - which * 384;
    const float* src = which == 0 ? wq : (which == 1 ? wk : wv);
    int h = r >> 6, e = r & 63;
    v = f2bf(src[h * 24576 + k * 64 + e]);
  }
  dst[t] = v;
}

// ---------------- layernorm f32-in -> bf16-out, wave per row ----------------
__global__ __launch_bounds__(256) void ln_kernel(const float* __restrict__ x,
                                                 const float* __restrict__ g,
                                                 const float* __restrict__ be,
                                                 unsigned short* __restrict__ out) {
  int wave = threadIdx.x >> 6, lane = threadIdx.x & 63;
  size_t row = (size_t)blockIdx.x * 4 + wave;
  const float* xr = x + row * DE;
  int c0 = lane * 2;
  float2 v0 = *(const float2*)(xr + c0);
  float2 v1 = *(const float2*)(xr + 128 + c0);
  float2 v2 = *(const float2*)(xr + 256 + c0);
  float s  = v0.x + v0.y + v1.x + v1.y + v2.x + v2.y;
  float ss = v0.x*v0.x + v0.y*v0.y + v1.x*v1.x + v1.y*v1.y + v2.x*v2.x + v2.y*v2.y;
#pragma unroll
  for (int m = 1; m < 64; m <<= 1) { s += __shfl_xor(s, m); ss += __shfl_xor(ss, m); }
  float mu = s * (1.0f / 384.0f);
  float rstd = rsqrtf(ss * (1.0f / 384.0f) - mu * mu + 1e-5f);
  unsigned short* orow = out + row * DE;
  {
    float a0 = (v0.x - mu) * rstd * g[c0] + be[c0];
    float a1 = (v0.y - mu) * rstd * g[c0 + 1] + be[c0 + 1];
    *(unsigned*)(orow + c0) = (unsigned)f2bf(a0) | ((unsigned)f2bf(a1) << 16);
  }
  {
    int c = c0 + 128;
    float a0 = (v1.x - mu) * rstd * g[c] + be[c];
    float a1 = (v1.y - mu) * rstd * g[c + 1] + be[c + 1];
    *(unsigned*)(orow + c) = (unsigned)f2bf(a0) | ((unsigned)f2bf(a1) << 16);
  }
  {
    int c = c0 + 256;
    float a0 = (v2.x - mu) * rstd * g[c] + be[c];
    float a1 = (v2.y - mu) * rstd * g[c + 1] + be[c + 1];
    *(unsigned*)(orow + c) = (unsigned)f2bf(a0) | ((unsigned)f2bf(a1) << 16);
  }
}

// ---------------- GEMM core, 32x32x16 MFMA: C[M,*] = A[M,K] @ Bt[*,K]^T ----------------
// Two-term swizzle: slot' = slot ^ (row&7) ^ ((row>>3)&3) — conflict-free for
// 32-row fragment reads (verified R11: SQ_LDS_BANK_CONFLICT = 0).
// C/D layout: col = lane&31, row = (reg&3) + 8*(reg>>2) + 4*(lane>>5)   [m74/m101]
template<int EPI, int BM, int BN, int WM, int WN>
__device__ __forceinline__
void gemm_core(const unsigned short* __restrict__ A, const unsigned short* __restrict__ Bt,
               int M, int K, int Nst, int stride, int ntx,
               const float* __restrict__ bias, const float* __restrict__ residf,
               const unsigned short* __restrict__ residb,
               const float* __restrict__ g2, const float* __restrict__ be2,
               float* __restrict__ outf, unsigned short* __restrict__ outb,
               unsigned short* __restrict__ out2) {
  constexpr int T = WM * WN * 64;
  constexpr int MWT = BM / WM, NWT = BN / WN;
  constexpr int MT = MWT / 32, NT = NWT / 32;       // 32x32 tiles per wave
  constexpr int LA = (BM * 128) / (T * 16);
  constexpr int LB = (BN * 128) / (T * 16);
  __shared__ __align__(16) unsigned short As[2][BM * 64];
  __shared__ __align__(16) unsigned short Bs[2][BN * 64];
  __shared__ float red[(EPI == 1) ? BM : 1][4][2];
  const int tid = threadIdx.x;
  const int wave = tid >> 6, lane = tid & 63;

  const int nwg = gridDim.x;
  const int cpx = nwg >> 3;
  const int wg = (blockIdx.x & 7) * cpx + (blockIdx.x >> 3);
  const int bx = wg % ntx, by = wg / ntx;
  const int mBase = by * BM, nBase = bx * BN;
  const int wmi = wave / WN, wni = wave % WN;
  const int wm = wmi * MWT, wn = wni * NWT;
  const int cr = lane & 31;          // row within 32-tile (A) / col (B, C)
  const int hg = lane >> 5;          // k half-group

  const unsigned asb = (unsigned)(uintptr_t)&As[0][0];
  const unsigned bsb = (unsigned)(uintptr_t)&Bs[0][0];

  f32x16 acc[MT][NT];
#pragma unroll
  for (int i = 0; i < MT; ++i)
#pragma unroll
    for (int j = 0; j < NT; ++j)
#pragma unroll
      for (int r = 0; r < 16; ++r) acc[i][j][r] = 0.f;

  auto stage = [&](int buf, int kt) {
#pragma unroll
    for (int i = 0; i < LA; ++i) {
      int Lb = i * (T * 16) + wave * 1024;   // wave-uniform LDS byte base
      int L = Lb + lane * 16;
      int row = L >> 7;
      int col = ((((L >> 4) & 7) ^ (row & 7) ^ ((row >> 3) & 3)) << 3);
      gll16(A + (size_t)(mBase + row) * K + kt + col, (unsigned short*)As[buf] + (Lb >> 1));
    }
#pragma unroll
    for (int i = 0; i < LB; ++i) {
      int Lb = i * (T * 16) + wave * 1024;
      int L = Lb + lane * 16;
      int row = L >> 7;
      int col = ((((L >> 4) & 7) ^ (row & 7) ^ ((row >> 3) & 3)) << 3);
      gll16(Bt + (size_t)(nBase + row) * K + kt + col, (unsigned short*)Bs[buf] + (Lb >> 1));
    }
  };

  const int NK = K >> 6;
  stage(0, 0);
  for (int t = 0; t < NK; ++t) {
    const int cur = t & 1;
    if (t + 1 < NK) {
      stage(cur ^ 1, (t + 1) << 6);
      if constexpr (LA + LB == 8)      asm volatile("s_waitcnt vmcnt(8)" ::: "memory");
      else if constexpr (LA + LB == 7) asm volatile("s_waitcnt vmcnt(7)" ::: "memory");
      else                             asm volatile("s_waitcnt vmcnt(6)" ::: "memory");
    } else {
      asm volatile("s_waitcnt vmcnt(0)" ::: "memory");
    }
    asm volatile("" ::: "memory");
    __builtin_amdgcn_s_barrier();
    asm volatile("" ::: "memory");

    const unsigned ab = asb + (cur ? (unsigned)(BM * 128) : 0u);
    const unsigned bb = bsb + (cur ? (unsigned)(BN * 128) : 0u);
    // 4 K-steps of 16; grouped 2 per cluster
#pragma unroll
    for (int k2 = 0; k2 < 2; ++k2) {
      bf16x8 bfr[2][NT], af[2][MT];
#pragma unroll
      for (int kk = 0; kk < 2; ++kk) {
        const int ks = k2 * 2 + kk;
#pragma unroll
        for (int nt = 0; nt < NT; ++nt) {
          int row = wn + nt * 32 + cr;
          unsigned slot = (unsigned)(((ks * 2 + hg) ^ (row & 7) ^ ((row >> 3) & 3)) & 7);
          bfr[kk][nt] = ds128(bb + (unsigned)(row << 7) + (slot << 4));
        }
#pragma unroll
        for (int mt = 0; mt < MT; ++mt) {
          int row = wm + mt * 32 + cr;
          unsigned slot = (unsigned)(((ks * 2 + hg) ^ (row & 7) ^ ((row >> 3) & 3)) & 7);
          af[kk][mt] = ds128(ab + (unsigned)(row << 7) + (slot << 4));
        }
      }
      asm volatile("s_waitcnt lgkmcnt(0)" ::: "memory");
      __builtin_amdgcn_sched_barrier(0);
      __builtin_amdgcn_s_setprio(1);
#pragma unroll
      for (int kk = 0; kk < 2; ++kk)
#pragma unroll
        for (int mt = 0; mt < MT; ++mt)
#pragma unroll
          for (int nt = 0; nt < NT; ++nt)
            acc[mt][nt] = __builtin_amdgcn_mfma_f32_32x32x16_bf16(af[kk][mt], bfr[kk][nt],
                                                                  acc[mt][nt], 0, 0, 0);
      __builtin_amdgcn_s_setprio(0);
    }
    asm volatile("" ::: "memory");
    __builtin_amdgcn_s_barrier();
    asm volatile("" ::: "memory");
  }

  if (EPI == 1) {
    // fused proj + LN2 (BN == full row width 384)
#pragma unroll
    for (int mt = 0; mt < MT; ++mt) {
#pragma unroll
      for (int nt = 0; nt < NT; ++nt) {
        const int gn = nBase + wn + nt * 32 + cr;
#pragma unroll
        for (int r = 0; r < 16; ++r) {
          const int gm = mBase + wm + mt * 32 + (r & 3) + ((r >> 2) << 3) + (hg << 2);
          size_t idx = (size_t)gm * stride + gn;
          acc[mt][nt][r] = acc[mt][nt][r] + bias[gn] + residf[idx];
        }
      }
    }
    // row partials over this wave's col slice, reduce across the 32 col lanes
#pragma unroll
    for (int mt = 0; mt < MT; ++mt) {
#pragma unroll
      for (int r = 0; r < 16; ++r) {
        float s = 0.f, ss = 0.f;
#pragma unroll
        for (int nt = 0; nt < NT; ++nt) {
          float v = acc[mt][nt][r];
          s += v; ss += v * v;
        }
        s += __shfl_xor(s, 1);  ss += __shfl_xor(ss, 1);
        s += __shfl_xor(s, 2);  ss += __shfl_xor(ss, 2);
        s += __shfl_xor(s, 4);  ss += __shfl_xor(ss, 4);
        s += __shfl_xor(s, 8);  ss += __shfl_xor(ss, 8);
        s += __shfl_xor(s, 16); ss += __shfl_xor(ss, 16);
        if (cr == 0) {
          int row = wm + mt * 32 + (r & 3) + ((r >> 2) << 3) + (hg << 2);
          red[row][wni][0] = s;
          red[row][wni][1] = ss;
        }
      }
    }
    __syncthreads();
#pragma unroll
    for (int mt = 0; mt < MT; ++mt) {
#pragma unroll
      for (int r = 0; r < 16; ++r) {
        int row = wm + mt * 32 + (r & 3) + ((r >> 2) << 3) + (hg << 2);
        float s = red[row][0][0] + red[row][1][0] + red[row][2][0] + red[row][3][0];
        float ss = red[row][0][1] + red[row][1][1] + red[row][2][1] + red[row][3][1];
        float mu = s * (1.0f / 384.0f);
        float rstd = rsqrtf(ss * (1.0f / 384.0f) - mu * mu + 1e-5f);
        const int gm = mBase + row;
#pragma unroll
        for (int nt = 0; nt < NT; ++nt) {
          const int gn = nBase + wn + nt * 32 + cr;
          size_t idx = (size_t)gm * stride + gn;
          float x1v = acc[mt][nt][r];
          outb[idx] = f2bf(x1v);
          out2[idx] = f2bf((x1v - mu) * rstd * g2[gn] + be2[gn]);
        }
      }
    }
    return;
  }

#pragma unroll
  for (int mt = 0; mt < MT; ++mt) {
#pragma unroll
    for (int nt = 0; nt < NT; ++nt) {
      const int gn = nBase + wn + nt * 32 + cr;
      if (gn < Nst) {
#pragma unroll
        for (int r = 0; r < 16; ++r) {
          const int gm = mBase + wm + mt * 32 + (r & 3) + ((r >> 2) << 3) + (hg << 2);
          float val = acc[mt][nt][r];
          size_t idx = (size_t)gm * stride + gn;
          if (EPI == 0) {
            outb[idx] = f2bf(val);
          } else if (EPI == 2) {
            float rr = val + bias[gn];
            outb[idx] = f2bf(rr > 0.f ? rr : 0.f);
          } else {
            outf[idx] = val + bias[gn] + b2f(residb[idx]);
          }
        }
      }
    }
  }
}

__global__ __launch_bounds__(512, 1)
void gemm_qkv(const unsigned short* __restrict__ A, const unsigned short* __restrict__ Bt,
              int M, int K, int Nst, int stride, int ntx,
              const float* __restrict__ bias, const float* __restrict__ residf,
              const unsigned short* __restrict__ residb, float* __restrict__ outf,
              unsigned short* __restrict__ outb) {
  gemm_core<0, 256, 192, 4, 2>(A, Bt, M, K, Nst, stride, ntx, bias, residf, residb,
                               nullptr, nullptr, outf, outb, nullptr);
}
__global__ __launch_bounds__(512, 1)
void gemm_projln(const unsigned short* __restrict__ A, const unsigned short* __restrict__ Bt,
                 int M, int K, int Nst, int stride, int ntx,
                 const float* __restrict__ bias, const float* __restrict__ residf,
                 const float* __restrict__ g2, const float* __restrict__ be2,
                 unsigned short* __restrict__ outb, unsigned short* __restrict__ out2) {
  gemm_core<1, 128, 384, 2, 4>(A, Bt, M, K, Nst, stride, ntx, bias, residf, nullptr,
                               g2, be2, nullptr, outb, out2);
}
__global__ __launch_bounds__(512, 1)
void gemm_mlp1(const unsigned short* __restrict__ A, const unsigned short* __restrict__ Bt,
               int M, int K, int Nst, int stride, int ntx,
               const float* __restrict__ bias, const float* __restrict__ residf,
               const unsigned short* __restrict__ residb, float* __restrict__ outf,
               unsigned short* __restrict__ outb) {
  gemm_core<2, 256, 256, 2, 4>(A, Bt, M, K, Nst, stride, ntx, bias, residf, residb,
                               nullptr, nullptr, outf, outb, nullptr);
}
__global__ __launch_bounds__(512, 1)
void gemm_mlp2(const unsigned short* __restrict__ A, const unsigned short* __restrict__ Bt,
               int M, int K, int Nst, int stride, int ntx,
               const float* __restrict__ bias, const float* __restrict__ residf,
               const unsigned short* __restrict__ residb, float* __restrict__ outf,
               unsigned short* __restrict__ outb) {
  gemm_core<3, 256, 128, 4, 2>(A, Bt, M, K, Nst, stride, ntx, bias, residf, residb,
                               nullptr, nullptr, outf, outb, nullptr);
}

// ---------------- attention: one block per (b,h), 4 waves x 64 Q-rows ----------------
// Single pass: softmax without max-subtraction (S*scale small; guarded fminf 60).
__global__ __launch_bounds__(256)
void attn_kernel(const unsigned short* __restrict__ qkvn, unsigned short* __restrict__ o) {
  __shared__ unsigned short Vt[64 * 256];   // V^T [e][s], 16B-slot XOR swizzled
  __shared__ unsigned short Pw[4][64 * 32];
  const int bh = blockIdx.x;
  const int b = bh / 6, h = bh - b * 6;
  const unsigned short* base = qkvn + (size_t)(b * 256) * QSTR;
  const unsigned short* qb = base + h * 64;
  const unsigned short* kbp = base + 384 + h * 64;
  const unsigned short* vbp = base + 768 + h * 64;
  const int wave = threadIdx.x >> 6, lane = threadIdx.x & 63;
  const int fr = lane & 15, fg = lane >> 4;
  const int fk = fg << 3;
  const int qrow0 = wave << 6;
  const float scale = 0.051031036307982884f;  // 1/sqrt(384)
  const f32x4 z = {0.f, 0.f, 0.f, 0.f};

  {
    const int s = threadIdx.x;
    u16x8 v8[8];
#pragma unroll
    for (int j = 0; j < 8; ++j)
      v8[j] = *(const u16x8*)(vbp + (size_t)s * QSTR + j * 8);
#pragma unroll
    for (int e = 0; e < 64; ++e)
      Vt[(e << 8) + (s ^ ((e & 7) << 3))] = v8[e >> 3][e & 7];
  }
  __syncthreads();

  bf16x8 qf[4][2];
#pragma unroll
  for (int rb = 0; rb < 4; ++rb)
#pragma unroll
    for (int ks = 0; ks < 2; ++ks)
      qf[rb][ks] = *(const bf16x8*)(qb + (size_t)(qrow0 + rb * 16 + fr) * QSTR + ks * 32 + fk);

  f32x4 oacc[4][4];
  float psum[4][4];
#pragma unroll
  for (int rb = 0; rb < 4; ++rb)
#pragma unroll
    for (int nb = 0; nb < 4; ++nb) oacc[rb][nb] = z;
#pragma unroll
  for (int rb = 0; rb < 4; ++rb)
#pragma unroll
    for (int i = 0; i < 4; ++i) psum[rb][i] = 0.f;

  for (int kb2 = 0; kb2 < 8; ++kb2) {
#pragma unroll
    for (int c2 = 0; c2 < 2; ++c2) {
      int cb = kb2 * 2 + c2;
      bf16x8 kf0 = *(const bf16x8*)(kbp + (size_t)(cb * 16 + fr) * QSTR + fk);
      bf16x8 kf1 = *(const bf16x8*)(kbp + (size_t)(cb * 16 + fr) * QSTR + 32 + fk);
#pragma unroll
      for (int rb = 0; rb < 4; ++rb) {
        f32x4 s = __builtin_amdgcn_mfma_f32_16x16x32_bf16(qf[rb][0], kf0, z, 0, 0, 0);
        s = __builtin_amdgcn_mfma_f32_16x16x32_bf16(qf[rb][1], kf1, s, 0, 0, 0);
#pragma unroll
        for (int i = 0; i < 4; ++i) {
          float p = __expf(fminf(scale * s[i], 60.f));
          psum[rb][i] += p;
          Pw[wave][(rb * 16 + (fg << 2) + i) * 32 + c2 * 16 + fr] = f2bf(p);
        }
      }
    }
    bf16x8 pa[4], vf[4];
#pragma unroll
    for (int rb = 0; rb < 4; ++rb) pa[rb] = *(const bf16x8*)(&Pw[wave][(rb * 16 + fr) * 32 + fk]);
#pragma unroll
    for (int nb = 0; nb < 4; ++nb) {
      int e = nb * 16 + fr;
      vf[nb] = *(const bf16x8*)(&Vt[(e << 8) + ((kb2 * 32 + fk) ^ ((e & 7) << 3))]);
    }
#pragma unroll
    for (int rb = 0; rb < 4; ++rb)
#pragma unroll
      for (int nb = 0; nb < 4; ++nb)
        oacc[rb][nb] = __builtin_amdgcn_mfma_f32_16x16x32_bf16(pa[rb], vf[nb], oacc[rb][nb], 0, 0, 0);
  }

  float rs[4][4];
#pragma unroll
  for (int rb = 0; rb < 4; ++rb)
#pragma unroll
    for (int i = 0; i < 4; ++i) {
      float v = psum[rb][i];
      v += __shfl_xor(v, 1);
      v += __shfl_xor(v, 2);
      v += __shfl_xor(v, 4);
      v += __shfl_xor(v, 8);
      rs[rb][i] = 1.0f / v;
    }

#pragma unroll
  for (int rb = 0; rb < 4; ++rb)
#pragma unroll
    for (int nb = 0; nb < 4; ++nb)
#pragma unroll
      for (int i = 0; i < 4; ++i) {
        int token = b * 256 + qrow0 + rb * 16 + (fg << 2) + i;
        int gcol = h * 64 + nb * 16 + fr;
        o[(size_t)token * DE + gcol] = f2bf(oacc[rb][nb][i] * rs[rb][i]);
      }
}

// ---------------- launch ----------------
extern "C" void kernel_launch(void* const* d_in, const int* in_sizes, int n_in,
                              void* d_out, int out_size, void* d_ws, size_t ws_size,
                              hipStream_t stream) {
  const float* x     = (const float*)d_in[0];
  const float* wq    = (const float*)d_in[1];
  const float* wk    = (const float*)d_in[2];
  const float* wv    = (const float*)d_in[3];
  const float* wproj = (const float*)d_in[4];
  const float* bproj = (const float*)d_in[5];
  const float* w1    = (const float*)d_in[6];
  const float* b1    = (const float*)d_in[7];
  const float* w2    = (const float*)d_in[8];
  const float* b2    = (const float*)d_in[9];
  const float* g1    = (const float*)d_in[10];
  const float* be1   = (const float*)d_in[11];
  const float* g2    = (const float*)d_in[12];
  const float* be2   = (const float*)d_in[13];

  char* ws = (char*)d_ws;
  // lifetime-overlapped layout:
  //  xln  @0          (50MB, dead after qkv) ; x1b @0 (50MB bf16, projln out, live->mlp2)
  //  qkvn @50331648   (168MB, dead after attn)
  //  hbuf @100663296  (50MB, LN2 out from projln, inside dead qkvn)
  //  act  @150994944  (201MB, mlp1 out)
  //  attno@218103808  (50MB, dead after proj)
  //  weights @352321536
  unsigned short* xln   = (unsigned short*)(ws + 0);
  unsigned short* x1b   = (unsigned short*)(ws + 0);
  unsigned short* qkvn  = (unsigned short*)(ws + 50331648);
  unsigned short* hbuf  = (unsigned short*)(ws + 100663296);
  unsigned short* act   = (unsigned short*)(ws + 150994944);
  unsigned short* attno = (unsigned short*)(ws + 218103808);
  unsigned short* wqkvt = (unsigned short*)(ws + 352321536);                        // 983040 B
  unsigned short* wprjt = (unsigned short*)(ws + 352321536 + 983040);               // 294912 B
  unsigned short* w1t   = (unsigned short*)(ws + 352321536 + 983040 + 294912);      // 1179648 B
  unsigned short* w2t   = (unsigned short*)(ws + 352321536 + 983040 + 294912 + 1179648);

  qkv_pack<<<(QSTR * 384 + 255) / 256, 256, 0, stream>>>(wq, wk, wv, wqkvt);
  pack_t<<<(147456 + 255) / 256, 256, 0, stream>>>(wprjt, wproj, 384, 384);
  pack_t<<<(589824 + 255) / 256, 256, 0, stream>>>(w1t, w1, 384, 1536);
  pack_t<<<(589824 + 255) / 256, 256, 0, stream>>>(w2t, w2, 1536, 384);

  ln_kernel<<<NTOK / 4, 256, 0, stream>>>(x, g1, be1, xln);

  // qkv: N computed = 1152 exactly (BN=192, ntx=6), storage stride 1280
  gemm_qkv<<<6 * 256, 512, 0, stream>>>(xln, wqkvt, NTOK, 384, 1152, 1280, 6,
                                        nullptr, nullptr, nullptr, nullptr, qkvn);

  attn_kernel<<<1536, 256, 0, stream>>>(qkvn, attno);

  // proj + LN2 fused: BM=128, BN=384 (full row per block), writes x1b + hbuf
  gemm_projln<<<512, 512, 0, stream>>>(attno, wprjt, NTOK, 384, 384, 384, 1,
                                       bproj, x, g2, be2, x1b, hbuf);

  gemm_mlp1<<<6 * 256, 512, 0, stream>>>(hbuf, w1t, NTOK, 384, 1536, 1536, 6,
                                         b1, nullptr, nullptr, nullptr, act);

  gemm_mlp2<<<3 * 256, 512, 0, stream>>>(act, w2t, NTOK, 1536, 384, 384, 3,
                                         b2, nullptr, x1b, (float*)d_out, nullptr);
}

// Round 17
// 510.184 us; speedup vs baseline: 1.1100x; 1.0126x over previous
//
#include <hip/hip_runtime.h>
#include <stdint.h>

#define NTOK 65536          // B*T
#define DE 384
#define QSTR 1280           // padded qkv row stride (1152 used)

typedef __bf16 bf16x8 __attribute__((ext_vector_type(8)));
typedef float  f32x4  __attribute__((ext_vector_type(4)));
typedef float  f32x16 __attribute__((ext_vector_type(16)));
typedef unsigned short u16x8 __attribute__((ext_vector_type(8)));

__device__ __forceinline__ unsigned short f2bf(float f) {
  union { float fl; unsigned u; } a; a.fl = f;
  unsigned r = a.u + 0x7fffu + ((a.u >> 16) & 1u);
  return (unsigned short)(r >> 16);
}
__device__ __forceinline__ float b2f(unsigned short s) {
  union { unsigned u; float f; } v; v.u = (unsigned)s << 16; return v.f;
}

__device__ __forceinline__ void gll16(const void* g, void* l) {
  __builtin_amdgcn_global_load_lds((const __attribute__((address_space(1))) void*)g,
                                   (__attribute__((address_space(3))) void*)l, 16, 0, 0);
}

__device__ __forceinline__ bf16x8 ds128(unsigned addr) {
  bf16x8 r;
  asm volatile("ds_read_b128 %0, %1" : "=v"(r) : "v"(addr));
  return r;
}

// ---------------- merged weight packing (one launch) ----------------
// blocks [0,1920):    Wqkv_t padded [1280][384], n = which*384 + h*64 + e
// blocks [1920,2496): wprjt = wproj^T  [384][384]
// blocks [2496,4800): w1t   = w1^T     [1536 cols of 384] -> [1536][384]? no: dst[c*R+r], R=384,C=1536
// blocks [4800,7104): w2t   = w2^T     R=1536,C=384
__global__ __launch_bounds__(256)
void pack_all(const float* __restrict__ wq, const float* __restrict__ wk,
              const float* __restrict__ wv, const float* __restrict__ wproj,
              const float* __restrict__ w1, const float* __restrict__ w2,
              unsigned short* __restrict__ wqkvt, unsigned short* __restrict__ wprjt,
              unsigned short* __restrict__ w1t, unsigned short* __restrict__ w2t) {
  const int blk = blockIdx.x;
  if (blk < 1920) {
    int t = blk * 256 + threadIdx.x;
    if (t >= QSTR * 384) return;
    int n = t / 384, k = t - n * 384;
    unsigned short v = 0;
    if (n < 1152) {
      int which = n / 384, r = n - which * 384;
      const float* src = which == 0 ? wq : (which == 1 ? wk : wv);
      int h = r >> 6, e = r & 63;
      v = f2bf(src[h * 24576 + k * 64 + e]);
    }
    wqkvt[t] = v;
  } else if (blk < 2496) {
    int t = (blk - 1920) * 256 + threadIdx.x;
    if (t >= 384 * 384) return;
    int r = t / 384, c = t - r * 384;
    wprjt[(size_t)c * 384 + r] = f2bf(wproj[t]);
  } else if (blk < 4800) {
    int t = (blk - 2496) * 256 + threadIdx.x;
    if (t >= 384 * 1536) return;
    int r = t / 1536, c = t - r * 1536;
    w1t[(size_t)c * 384 + r] = f2bf(w1[t]);
  } else {
    int t = (blk - 4800) * 256 + threadIdx.x;
    if (t >= 1536 * 384) return;
    int r = t / 384, c = t - r * 384;
    w2t[(size_t)c * 1536 + r] = f2bf(w2[t]);
  }
}

// ---------------- layernorm f32-in -> bf16-out, wave per row ----------------
__global__ __launch_bounds__(256) void ln_kernel(const float* __restrict__ x,
                                                 const float* __restrict__ g,
                                                 const float* __restrict__ be,
                                                 unsigned short* __restrict__ out) {
  int wave = threadIdx.x >> 6, lane = threadIdx.x & 63;
  size_t row = (size_t)blockIdx.x * 4 + wave;
  const float* xr = x + row * DE;
  int c0 = lane * 2;
  float2 v0 = *(const float2*)(xr + c0);
  float2 v1 = *(const float2*)(xr + 128 + c0);
  float2 v2 = *(const float2*)(xr + 256 + c0);
  float s  = v0.x + v0.y + v1.x + v1.y + v2.x + v2.y;
  float ss = v0.x*v0.x + v0.y*v0.y + v1.x*v1.x + v1.y*v1.y + v2.x*v2.x + v2.y*v2.y;
#pragma unroll
  for (int m = 1; m < 64; m <<= 1) { s += __shfl_xor(s, m); ss += __shfl_xor(ss, m); }
  float mu = s * (1.0f / 384.0f);
  float rstd = rsqrtf(ss * (1.0f / 384.0f) - mu * mu + 1e-5f);
  unsigned short* orow = out + row * DE;
  {
    float a0 = (v0.x - mu) * rstd * g[c0] + be[c0];
    float a1 = (v0.y - mu) * rstd * g[c0 + 1] + be[c0 + 1];
    *(unsigned*)(orow + c0) = (unsigned)f2bf(a0) | ((unsigned)f2bf(a1) << 16);
  }
  {
    int c = c0 + 128;
    float a0 = (v1.x - mu) * rstd * g[c] + be[c];
    float a1 = (v1.y - mu) * rstd * g[c + 1] + be[c + 1];
    *(unsigned*)(orow + c) = (unsigned)f2bf(a0) | ((unsigned)f2bf(a1) << 16);
  }
  {
    int c = c0 + 256;
    float a0 = (v2.x - mu) * rstd * g[c] + be[c];
    float a1 = (v2.y - mu) * rstd * g[c + 1] + be[c + 1];
    *(unsigned*)(orow + c) = (unsigned)f2bf(a0) | ((unsigned)f2bf(a1) << 16);
  }
}

// ---------------- GEMM core, 32x32x16 MFMA: C[M,*] = A[M,K] @ Bt[*,K]^T ----------------
// Two-term swizzle: slot' = slot ^ (row&7) ^ ((row>>3)&3) — conflict-free for
// 32-row fragment reads (verified R11: SQ_LDS_BANK_CONFLICT = 0).
// C/D layout: col = lane&31, row = (reg&3) + 8*(reg>>2) + 4*(lane>>5)   [m74/m101]
template<int EPI, int BM, int BN, int WM, int WN>
__device__ __forceinline__
void gemm_core(const unsigned short* __restrict__ A, const unsigned short* __restrict__ Bt,
               int M, int K, int Nst, int stride, int ntx,
               const float* __restrict__ bias, const float* __restrict__ residf,
               const unsigned short* __restrict__ residb,
               const float* __restrict__ g2, const float* __restrict__ be2,
               float* __restrict__ outf, unsigned short* __restrict__ outb,
               unsigned short* __restrict__ out2) {
  constexpr int T = WM * WN * 64;
  constexpr int MWT = BM / WM, NWT = BN / WN;
  constexpr int MT = MWT / 32, NT = NWT / 32;       // 32x32 tiles per wave
  constexpr int LA = (BM * 128) / (T * 16);
  constexpr int LB = (BN * 128) / (T * 16);
  __shared__ __align__(16) unsigned short As[2][BM * 64];
  __shared__ __align__(16) unsigned short Bs[2][BN * 64];
  __shared__ float red[(EPI == 1) ? BM : 1][4][2];
  const int tid = threadIdx.x;
  const int wave = tid >> 6, lane = tid & 63;

  const int nwg = gridDim.x;
  const int cpx = nwg >> 3;
  const int wg = (blockIdx.x & 7) * cpx + (blockIdx.x >> 3);
  const int bx = wg % ntx, by = wg / ntx;
  const int mBase = by * BM, nBase = bx * BN;
  const int wmi = wave / WN, wni = wave % WN;
  const int wm = wmi * MWT, wn = wni * NWT;
  const int cr = lane & 31;          // row within 32-tile (A) / col (B, C)
  const int hg = lane >> 5;          // k half-group

  const unsigned asb = (unsigned)(uintptr_t)&As[0][0];
  const unsigned bsb = (unsigned)(uintptr_t)&Bs[0][0];

  f32x16 acc[MT][NT];
#pragma unroll
  for (int i = 0; i < MT; ++i)
#pragma unroll
    for (int j = 0; j < NT; ++j)
#pragma unroll
      for (int r = 0; r < 16; ++r) acc[i][j][r] = 0.f;

  auto stage = [&](int buf, int kt) {
#pragma unroll
    for (int i = 0; i < LA; ++i) {
      int Lb = i * (T * 16) + wave * 1024;   // wave-uniform LDS byte base
      int L = Lb + lane * 16;
      int row = L >> 7;
      int col = ((((L >> 4) & 7) ^ (row & 7) ^ ((row >> 3) & 3)) << 3);
      gll16(A + (size_t)(mBase + row) * K + kt + col, (unsigned short*)As[buf] + (Lb >> 1));
    }
#pragma unroll
    for (int i = 0; i < LB; ++i) {
      int Lb = i * (T * 16) + wave * 1024;
      int L = Lb + lane * 16;
      int row = L >> 7;
      int col = ((((L >> 4) & 7) ^ (row & 7) ^ ((row >> 3) & 3)) << 3);
      gll16(Bt + (size_t)(nBase + row) * K + kt + col, (unsigned short*)Bs[buf] + (Lb >> 1));
    }
  };

  const int NK = K >> 6;
  stage(0, 0);
  for (int t = 0; t < NK; ++t) {
    const int cur = t & 1;
    if (t + 1 < NK) {
      stage(cur ^ 1, (t + 1) << 6);
      if constexpr (LA + LB == 8)      asm volatile("s_waitcnt vmcnt(8)" ::: "memory");
      else if constexpr (LA + LB == 7) asm volatile("s_waitcnt vmcnt(7)" ::: "memory");
      else                             asm volatile("s_waitcnt vmcnt(6)" ::: "memory");
    } else {
      asm volatile("s_waitcnt vmcnt(0)" ::: "memory");
    }
    asm volatile("" ::: "memory");
    __builtin_amdgcn_s_barrier();
    asm volatile("" ::: "memory");

    const unsigned ab = asb + (cur ? (unsigned)(BM * 128) : 0u);
    const unsigned bb = bsb + (cur ? (unsigned)(BN * 128) : 0u);
    // 4 K-steps of 16; grouped 2 per cluster
#pragma unroll
    for (int k2 = 0; k2 < 2; ++k2) {
      bf16x8 bfr[2][NT], af[2][MT];
#pragma unroll
      for (int kk = 0; kk < 2; ++kk) {
        const int ks = k2 * 2 + kk;
#pragma unroll
        for (int nt = 0; nt < NT; ++nt) {
          int row = wn + nt * 32 + cr;
          unsigned slot = (unsigned)(((ks * 2 + hg) ^ (row & 7) ^ ((row >> 3) & 3)) & 7);
          bfr[kk][nt] = ds128(bb + (unsigned)(row << 7) + (slot << 4));
        }
#pragma unroll
        for (int mt = 0; mt < MT; ++mt) {
          int row = wm + mt * 32 + cr;
          unsigned slot = (unsigned)(((ks * 2 + hg) ^ (row & 7) ^ ((row >> 3) & 3)) & 7);
          af[kk][mt] = ds128(ab + (unsigned)(row << 7) + (slot << 4));
        }
      }
      asm volatile("s_waitcnt lgkmcnt(0)" ::: "memory");
      __builtin_amdgcn_sched_barrier(0);
      __builtin_amdgcn_s_setprio(1);
#pragma unroll
      for (int kk = 0; kk < 2; ++kk)
#pragma unroll
        for (int mt = 0; mt < MT; ++mt)
#pragma unroll
          for (int nt = 0; nt < NT; ++nt)
            acc[mt][nt] = __builtin_amdgcn_mfma_f32_32x32x16_bf16(af[kk][mt], bfr[kk][nt],
                                                                  acc[mt][nt], 0, 0, 0);
      __builtin_amdgcn_s_setprio(0);
    }
    asm volatile("" ::: "memory");
    __builtin_amdgcn_s_barrier();
    asm volatile("" ::: "memory");
  }

  if (EPI == 1) {
    // fused proj + LN2 (BN == full row width 384)
#pragma unroll
    for (int mt = 0; mt < MT; ++mt) {
#pragma unroll
      for (int nt = 0; nt < NT; ++nt) {
        const int gn = nBase + wn + nt * 32 + cr;
#pragma unroll
        for (int r = 0; r < 16; ++r) {
          const int gm = mBase + wm + mt * 32 + (r & 3) + ((r >> 2) << 3) + (hg << 2);
          size_t idx = (size_t)gm * stride + gn;
          acc[mt][nt][r] = acc[mt][nt][r] + bias[gn] + residf[idx];
        }
      }
    }
    // row partials over this wave's col slice, reduce across the 32 col lanes
#pragma unroll
    for (int mt = 0; mt < MT; ++mt) {
#pragma unroll
      for (int r = 0; r < 16; ++r) {
        float s = 0.f, ss = 0.f;
#pragma unroll
        for (int nt = 0; nt < NT; ++nt) {
          float v = acc[mt][nt][r];
          s += v; ss += v * v;
        }
        s += __shfl_xor(s, 1);  ss += __shfl_xor(ss, 1);
        s += __shfl_xor(s, 2);  ss += __shfl_xor(ss, 2);
        s += __shfl_xor(s, 4);  ss += __shfl_xor(ss, 4);
        s += __shfl_xor(s, 8);  ss += __shfl_xor(ss, 8);
        s += __shfl_xor(s, 16); ss += __shfl_xor(ss, 16);
        if (cr == 0) {
          int row = wm + mt * 32 + (r & 3) + ((r >> 2) << 3) + (hg << 2);
          red[row][wni][0] = s;
          red[row][wni][1] = ss;
        }
      }
    }
    __syncthreads();
#pragma unroll
    for (int mt = 0; mt < MT; ++mt) {
#pragma unroll
      for (int r = 0; r < 16; ++r) {
        int row = wm + mt * 32 + (r & 3) + ((r >> 2) << 3) + (hg << 2);
        float s = red[row][0][0] + red[row][1][0] + red[row][2][0] + red[row][3][0];
        float ss = red[row][0][1] + red[row][1][1] + red[row][2][1] + red[row][3][1];
        float mu = s * (1.0f / 384.0f);
        float rstd = rsqrtf(ss * (1.0f / 384.0f) - mu * mu + 1e-5f);
        const int gm = mBase + row;
#pragma unroll
        for (int nt = 0; nt < NT; ++nt) {
          const int gn = nBase + wn + nt * 32 + cr;
          size_t idx = (size_t)gm * stride + gn;
          float x1v = acc[mt][nt][r];
          outb[idx] = f2bf(x1v);
          out2[idx] = f2bf((x1v - mu) * rstd * g2[gn] + be2[gn]);
        }
      }
    }
    return;
  }

#pragma unroll
  for (int mt = 0; mt < MT; ++mt) {
#pragma unroll
    for (int nt = 0; nt < NT; ++nt) {
      const int gn = nBase + wn + nt * 32 + cr;
      if (gn < Nst) {
#pragma unroll
        for (int r = 0; r < 16; ++r) {
          const int gm = mBase + wm + mt * 32 + (r & 3) + ((r >> 2) << 3) + (hg << 2);
          float val = acc[mt][nt][r];
          size_t idx = (size_t)gm * stride + gn;
          if (EPI == 0) {
            outb[idx] = f2bf(val);
          } else if (EPI == 2) {
            float rr = val + bias[gn];
            outb[idx] = f2bf(rr > 0.f ? rr : 0.f);
          } else {
            outf[idx] = val + bias[gn] + b2f(residb[idx]);
          }
        }
      }
    }
  }
}

__global__ __launch_bounds__(512, 1)
void gemm_qkv(const unsigned short* __restrict__ A, const unsigned short* __restrict__ Bt,
              int M, int K, int Nst, int stride, int ntx,
              const float* __restrict__ bias, const float* __restrict__ residf,
              const unsigned short* __restrict__ residb, float* __restrict__ outf,
              unsigned short* __restrict__ outb) {
  gemm_core<0, 256, 192, 4, 2>(A, Bt, M, K, Nst, stride, ntx, bias, residf, residb,
                               nullptr, nullptr, outf, outb, nullptr);
}
__global__ __launch_bounds__(512, 1)
void gemm_projln(const unsigned short* __restrict__ A, const unsigned short* __restrict__ Bt,
                 int M, int K, int Nst, int stride, int ntx,
                 const float* __restrict__ bias, const float* __restrict__ residf,
                 const float* __restrict__ g2, const float* __restrict__ be2,
                 unsigned short* __restrict__ outb, unsigned short* __restrict__ out2) {
  gemm_core<1, 128, 384, 2, 4>(A, Bt, M, K, Nst, stride, ntx, bias, residf, nullptr,
                               g2, be2, nullptr, outb, out2);
}
__global__ __launch_bounds__(512, 1)
void gemm_mlp1(const unsigned short* __restrict__ A, const unsigned short* __restrict__ Bt,
               int M, int K, int Nst, int stride, int ntx,
               const float* __restrict__ bias, const float* __restrict__ residf,
               const unsigned short* __restrict__ residb, float* __restrict__ outf,
               unsigned short* __restrict__ outb) {
  gemm_core<2, 256, 256, 2, 4>(A, Bt, M, K, Nst, stride, ntx, bias, residf, residb,
                               nullptr, nullptr, outf, outb, nullptr);
}
__global__ __launch_bounds__(512, 1)
void gemm_mlp2(const unsigned short* __restrict__ A, const unsigned short* __restrict__ Bt,
               int M, int K, int Nst, int stride, int ntx,
               const float* __restrict__ bias, const float* __restrict__ residf,
               const unsigned short* __restrict__ residb, float* __restrict__ outf,
               unsigned short* __restrict__ outb) {
  gemm_core<3, 256, 128, 4, 2>(A, Bt, M, K, Nst, stride, ntx, bias, residf, residb,
                               nullptr, nullptr, outf, outb, nullptr);
}

// ---------------- attention: one block per (b,h), 4 waves x 64 Q-rows ----------------
// Single pass: softmax without max-subtraction (S*scale small; guarded fminf 60).
__global__ __launch_bounds__(256)
void attn_kernel(const unsigned short* __restrict__ qkvn, unsigned short* __restrict__ o) {
  __shared__ unsigned short Vt[64 * 256];   // V^T [e][s], 16B-slot XOR swizzled
  __shared__ unsigned short Pw[4][64 * 32];
  const int bh = blockIdx.x;
  const int b = bh / 6, h = bh - b * 6;
  const unsigned short* base = qkvn + (size_t)(b * 256) * QSTR;
  const unsigned short* qb = base + h * 64;
  const unsigned short* kbp = base + 384 + h * 64;
  const unsigned short* vbp = base + 768 + h * 64;
  const int wave = threadIdx.x >> 6, lane = threadIdx.x & 63;
  const int fr = lane & 15, fg = lane >> 4;
  const int fk = fg << 3;
  const int qrow0 = wave << 6;
  const float scale = 0.051031036307982884f;  // 1/sqrt(384)
  const f32x4 z = {0.f, 0.f, 0.f, 0.f};

  {
    const int s = threadIdx.x;
    u16x8 v8[8];
#pragma unroll
    for (int j = 0; j < 8; ++j)
      v8[j] = *(const u16x8*)(vbp + (size_t)s * QSTR + j * 8);
#pragma unroll
    for (int e = 0; e < 64; ++e)
      Vt[(e << 8) + (s ^ ((e & 7) << 3))] = v8[e >> 3][e & 7];
  }
  __syncthreads();

  bf16x8 qf[4][2];
#pragma unroll
  for (int rb = 0; rb < 4; ++rb)
#pragma unroll
    for (int ks = 0; ks < 2; ++ks)
      qf[rb][ks] = *(const bf16x8*)(qb + (size_t)(qrow0 + rb * 16 + fr) * QSTR + ks * 32 + fk);

  f32x4 oacc[4][4];
  float psum[4][4];
#pragma unroll
  for (int rb = 0; rb < 4; ++rb)
#pragma unroll
    for (int nb = 0; nb < 4; ++nb) oacc[rb][nb] = z;
#pragma unroll
  for (int rb = 0; rb < 4; ++rb)
#pragma unroll
    for (int i = 0; i < 4; ++i) psum[rb][i] = 0.f;

  for (int kb2 = 0; kb2 < 8; ++kb2) {
#pragma unroll
    for (int c2 = 0; c2 < 2; ++c2) {
      int cb = kb2 * 2 + c2;
      bf16x8 kf0 = *(const bf16x8*)(kbp + (size_t)(cb * 16 + fr) * QSTR + fk);
      bf16x8 kf1 = *(const bf16x8*)(kbp + (size_t)(cb * 16 + fr) * QSTR + 32 + fk);
#pragma unroll
      for (int rb = 0; rb < 4; ++rb) {
        f32x4 s = __builtin_amdgcn_mfma_f32_16x16x32_bf16(qf[rb][0], kf0, z, 0, 0, 0);
        s = __builtin_amdgcn_mfma_f32_16x16x32_bf16(qf[rb][1], kf1, s, 0, 0, 0);
#pragma unroll
        for (int i = 0; i < 4; ++i) {
          float p = __expf(fminf(scale * s[i], 60.f));
          psum[rb][i] += p;
          Pw[wave][(rb * 16 + (fg << 2) + i) * 32 + c2 * 16 + fr] = f2bf(p);
        }
      }
    }
    bf16x8 pa[4], vf[4];
#pragma unroll
    for (int rb = 0; rb < 4; ++rb) pa[rb] = *(const bf16x8*)(&Pw[wave][(rb * 16 + fr) * 32 + fk]);
#pragma unroll
    for (int nb = 0; nb < 4; ++nb) {
      int e = nb * 16 + fr;
      vf[nb] = *(const bf16x8*)(&Vt[(e << 8) + ((kb2 * 32 + fk) ^ ((e & 7) << 3))]);
    }
#pragma unroll
    for (int rb = 0; rb < 4; ++rb)
#pragma unroll
      for (int nb = 0; nb < 4; ++nb)
        oacc[rb][nb] = __builtin_amdgcn_mfma_f32_16x16x32_bf16(pa[rb], vf[nb], oacc[rb][nb], 0, 0, 0);
  }

  float rs[4][4];
#pragma unroll
  for (int rb = 0; rb < 4; ++rb)
#pragma unroll
    for (int i = 0; i < 4; ++i) {
      float v = psum[rb][i];
      v += __shfl_xor(v, 1);
      v += __shfl_xor(v, 2);
      v += __shfl_xor(v, 4);
      v += __shfl_xor(v, 8);
      rs[rb][i] = 1.0f / v;
    }

#pragma unroll
  for (int rb = 0; rb < 4; ++rb)
#pragma unroll
    for (int nb = 0; nb < 4; ++nb)
#pragma unroll
      for (int i = 0; i < 4; ++i) {
        int token = b * 256 + qrow0 + rb * 16 + (fg << 2) + i;
        int gcol = h * 64 + nb * 16 + fr;
        o[(size_t)token * DE + gcol] = f2bf(oacc[rb][nb][i] * rs[rb][i]);
      }
}

// ---------------- launch ----------------
extern "C" void kernel_launch(void* const* d_in, const int* in_sizes, int n_in,
                              void* d_out, int out_size, void* d_ws, size_t ws_size,
                              hipStream_t stream) {
  const float* x     = (const float*)d_in[0];
  const float* wq    = (const float*)d_in[1];
  const float* wk    = (const float*)d_in[2];
  const float* wv    = (const float*)d_in[3];
  const float* wproj = (const float*)d_in[4];
  const float* bproj = (const float*)d_in[5];
  const float* w1    = (const float*)d_in[6];
  const float* b1    = (const float*)d_in[7];
  const float* w2    = (const float*)d_in[8];
  const float* b2    = (const float*)d_in[9];
  const float* g1    = (const float*)d_in[10];
  const float* be1   = (const float*)d_in[11];
  const float* g2    = (const float*)d_in[12];
  const float* be2   = (const float*)d_in[13];

  char* ws = (char*)d_ws;
  // lifetime-overlapped layout:
  //  xln  @0          (50MB, dead after qkv) ; x1b @0 (50MB bf16, projln out, live->mlp2)
  //  qkvn @50331648   (168MB, dead after attn)
  //  hbuf @100663296  (50MB, LN2 out from projln, inside dead qkvn)
  //  act  @150994944  (201MB, mlp1 out)
  //  attno@218103808  (50MB, dead after proj)
  //  weights @352321536
  unsigned short* xln   = (unsigned short*)(ws + 0);
  unsigned short* x1b   = (unsigned short*)(ws + 0);
  unsigned short* qkvn  = (unsigned short*)(ws + 50331648);
  unsigned short* hbuf  = (unsigned short*)(ws + 100663296);
  unsigned short* act   = (unsigned short*)(ws + 150994944);
  unsigned short* attno = (unsigned short*)(ws + 218103808);
  unsigned short* wqkvt = (unsigned short*)(ws + 352321536);                        // 983040 B
  unsigned short* wprjt = (unsigned short*)(ws + 352321536 + 983040);               // 294912 B
  unsigned short* w1t   = (unsigned short*)(ws + 352321536 + 983040 + 294912);      // 1179648 B
  unsigned short* w2t   = (unsigned short*)(ws + 352321536 + 983040 + 294912 + 1179648);

  pack_all<<<7104, 256, 0, stream>>>(wq, wk, wv, wproj, w1, w2,
                                     wqkvt, wprjt, w1t, w2t);

  ln_kernel<<<NTOK / 4, 256, 0, stream>>>(x, g1, be1, xln);

  // qkv: N computed = 1152 exactly (BN=192, ntx=6), storage stride 1280
  gemm_qkv<<<6 * 256, 512, 0, stream>>>(xln, wqkvt, NTOK, 384, 1152, 1280, 6,
                                        nullptr, nullptr, nullptr, nullptr, qkvn);

  attn_kernel<<<1536, 256, 0, stream>>>(qkvn, attno);

  // proj + LN2 fused: BM=128, BN=384 (full row per block), writes x1b + hbuf
  gemm_projln<<<512, 512, 0, stream>>>(attno, wprjt, NTOK, 384, 384, 384, 1,
                                       bproj, x, g2, be2, x1b, hbuf);

  gemm_mlp1<<<6 * 256, 512, 0, stream>>>(hbuf, w1t, NTOK, 384, 1536, 1536, 6,
                                         b1, nullptr, nullptr, nullptr, act);

  gemm_mlp2<<<3 * 256, 512, 0, stream>>>(act, w2t, NTOK, 1536, 384, 384, 3,
                                         b2, nullptr, x1b, (float*)d_out, nullptr);
}

// Round 18
// 509.324 us; speedup vs baseline: 1.1119x; 1.0017x over previous
//
#include <hip/hip_runtime.h>
#include <stdint.h>

#define NTOK 65536          // B*T
#define DE 384
#define QSTR 1280           // padded qkv row stride (1152 used)

typedef __bf16 bf16x8 __attribute__((ext_vector_type(8)));
typedef float  f32x4  __attribute__((ext_vector_type(4)));
typedef float  f32x16 __attribute__((ext_vector_type(16)));
typedef unsigned short u16x8 __attribute__((ext_vector_type(8)));

__device__ __forceinline__ unsigned short f2bf(float f) {
  union { float fl; unsigned u; } a; a.fl = f;
  unsigned r = a.u + 0x7fffu + ((a.u >> 16) & 1u);
  return (unsigned short)(r >> 16);
}
__device__ __forceinline__ float b2f(unsigned short s) {
  union { unsigned u; float f; } v; v.u = (unsigned)s << 16; return v.f;
}

__device__ __forceinline__ void gll16(const void* g, void* l) {
  __builtin_amdgcn_global_load_lds((const __attribute__((address_space(1))) void*)g,
                                   (__attribute__((address_space(3))) void*)l, 16, 0, 0);
}

__device__ __forceinline__ bf16x8 ds128(unsigned addr) {
  bf16x8 r;
  asm volatile("ds_read_b128 %0, %1" : "=v"(r) : "v"(addr));
  return r;
}

// ---------------- merged weight packing (one launch) ----------------
__global__ __launch_bounds__(256)
void pack_all(const float* __restrict__ wq, const float* __restrict__ wk,
              const float* __restrict__ wv, const float* __restrict__ wproj,
              const float* __restrict__ w1, const float* __restrict__ w2,
              unsigned short* __restrict__ wqkvt, unsigned short* __restrict__ wprjt,
              unsigned short* __restrict__ w1t, unsigned short* __restrict__ w2t) {
  const int blk = blockIdx.x;
  if (blk < 1920) {
    int t = blk * 256 + threadIdx.x;
    if (t >= QSTR * 384) return;
    int n = t / 384, k = t - n * 384;
    unsigned short v = 0;
    if (n < 1152) {
      int which = n / 384, r = n - which * 384;
      const float* src = which == 0 ? wq : (which == 1 ? wk : wv);
      int h = r >> 6, e = r & 63;
      v = f2bf(src[h * 24576 + k * 64 + e]);
    }
    wqkvt[t] = v;
  } else if (blk < 2496) {
    int t = (blk - 1920) * 256 + threadIdx.x;
    if (t >= 384 * 384) return;
    int r = t / 384, c = t - r * 384;
    wprjt[(size_t)c * 384 + r] = f2bf(wproj[t]);
  } else if (blk < 4800) {
    int t = (blk - 2496) * 256 + threadIdx.x;
    if (t >= 384 * 1536) return;
    int r = t / 1536, c = t - r * 1536;
    w1t[(size_t)c * 384 + r] = f2bf(w1[t]);
  } else {
    int t = (blk - 4800) * 256 + threadIdx.x;
    if (t >= 1536 * 384) return;
    int r = t / 384, c = t - r * 384;
    w2t[(size_t)c * 1536 + r] = f2bf(w2[t]);
  }
}

// ---------------- layernorm f32-in -> bf16-out, wave per row ----------------
__global__ __launch_bounds__(256) void ln_kernel(const float* __restrict__ x,
                                                 const float* __restrict__ g,
                                                 const float* __restrict__ be,
                                                 unsigned short* __restrict__ out) {
  int wave = threadIdx.x >> 6, lane = threadIdx.x & 63;
  size_t row = (size_t)blockIdx.x * 4 + wave;
  const float* xr = x + row * DE;
  int c0 = lane * 2;
  float2 v0 = *(const float2*)(xr + c0);
  float2 v1 = *(const float2*)(xr + 128 + c0);
  float2 v2 = *(const float2*)(xr + 256 + c0);
  float s  = v0.x + v0.y + v1.x + v1.y + v2.x + v2.y;
  float ss = v0.x*v0.x + v0.y*v0.y + v1.x*v1.x + v1.y*v1.y + v2.x*v2.x + v2.y*v2.y;
#pragma unroll
  for (int m = 1; m < 64; m <<= 1) { s += __shfl_xor(s, m); ss += __shfl_xor(ss, m); }
  float mu = s * (1.0f / 384.0f);
  float rstd = rsqrtf(ss * (1.0f / 384.0f) - mu * mu + 1e-5f);
  unsigned short* orow = out + row * DE;
  {
    float a0 = (v0.x - mu) * rstd * g[c0] + be[c0];
    float a1 = (v0.y - mu) * rstd * g[c0 + 1] + be[c0 + 1];
    *(unsigned*)(orow + c0) = (unsigned)f2bf(a0) | ((unsigned)f2bf(a1) << 16);
  }
  {
    int c = c0 + 128;
    float a0 = (v1.x - mu) * rstd * g[c] + be[c];
    float a1 = (v1.y - mu) * rstd * g[c + 1] + be[c + 1];
    *(unsigned*)(orow + c) = (unsigned)f2bf(a0) | ((unsigned)f2bf(a1) << 16);
  }
  {
    int c = c0 + 256;
    float a0 = (v2.x - mu) * rstd * g[c] + be[c];
    float a1 = (v2.y - mu) * rstd * g[c + 1] + be[c + 1];
    *(unsigned*)(orow + c) = (unsigned)f2bf(a0) | ((unsigned)f2bf(a1) << 16);
  }
}

// ---------------- GEMM core, 32x32x16 MFMA: C[M,*] = A[M,K] @ Bt[*,K]^T ----------------
// Two-term swizzle: slot' = slot ^ (row&7) ^ ((row>>3)&3) — conflict-free for
// 32-row fragment reads (verified R11: SQ_LDS_BANK_CONFLICT = 0).
// C/D layout: col = lane&31, row = (reg&3) + 8*(reg>>2) + 4*(lane>>5)   [m74/m101]
template<int EPI, int BM, int BN, int WM, int WN>
__device__ __forceinline__
void gemm_core(const unsigned short* __restrict__ A, const unsigned short* __restrict__ Bt,
               int M, int K, int Nst, int stride, int ntx,
               const float* __restrict__ bias, const float* __restrict__ residf,
               const unsigned short* __restrict__ residb,
               const float* __restrict__ g2, const float* __restrict__ be2,
               float* __restrict__ outf, unsigned short* __restrict__ outb,
               unsigned short* __restrict__ out2) {
  constexpr int T = WM * WN * 64;
  constexpr int MWT = BM / WM, NWT = BN / WN;
  constexpr int MT = MWT / 32, NT = NWT / 32;       // 32x32 tiles per wave
  constexpr int LA = (BM * 128) / (T * 16);
  constexpr int LB = (BN * 128) / (T * 16);
  __shared__ __align__(16) unsigned short As[2][BM * 64];
  __shared__ __align__(16) unsigned short Bs[2][BN * 64];
  __shared__ float red[(EPI == 1) ? BM : 1][4][2];
  const int tid = threadIdx.x;
  const int wave = tid >> 6, lane = tid & 63;

  const int nwg = gridDim.x;
  const int cpx = nwg >> 3;
  const int wg = (blockIdx.x & 7) * cpx + (blockIdx.x >> 3);
  const int bx = wg % ntx, by = wg / ntx;
  const int mBase = by * BM, nBase = bx * BN;
  const int wmi = wave / WN, wni = wave % WN;
  const int wm = wmi * MWT, wn = wni * NWT;
  const int cr = lane & 31;          // row within 32-tile (A) / col (B, C)
  const int hg = lane >> 5;          // k half-group

  const unsigned asb = (unsigned)(uintptr_t)&As[0][0];
  const unsigned bsb = (unsigned)(uintptr_t)&Bs[0][0];

  f32x16 acc[MT][NT];
#pragma unroll
  for (int i = 0; i < MT; ++i)
#pragma unroll
    for (int j = 0; j < NT; ++j)
#pragma unroll
      for (int r = 0; r < 16; ++r) acc[i][j][r] = 0.f;

  auto stage = [&](int buf, int kt) {
#pragma unroll
    for (int i = 0; i < LA; ++i) {
      int Lb = i * (T * 16) + wave * 1024;   // wave-uniform LDS byte base
      int L = Lb + lane * 16;
      int row = L >> 7;
      int col = ((((L >> 4) & 7) ^ (row & 7) ^ ((row >> 3) & 3)) << 3);
      gll16(A + (size_t)(mBase + row) * K + kt + col, (unsigned short*)As[buf] + (Lb >> 1));
    }
#pragma unroll
    for (int i = 0; i < LB; ++i) {
      int Lb = i * (T * 16) + wave * 1024;
      int L = Lb + lane * 16;
      int row = L >> 7;
      int col = ((((L >> 4) & 7) ^ (row & 7) ^ ((row >> 3) & 3)) << 3);
      gll16(Bt + (size_t)(nBase + row) * K + kt + col, (unsigned short*)Bs[buf] + (Lb >> 1));
    }
  };

  const int NK = K >> 6;
  stage(0, 0);
  for (int t = 0; t < NK; ++t) {
    const int cur = t & 1;
    if (t + 1 < NK) {
      stage(cur ^ 1, (t + 1) << 6);
      if constexpr (LA + LB == 8)      asm volatile("s_waitcnt vmcnt(8)" ::: "memory");
      else if constexpr (LA + LB == 7) asm volatile("s_waitcnt vmcnt(7)" ::: "memory");
      else                             asm volatile("s_waitcnt vmcnt(6)" ::: "memory");
    } else {
      asm volatile("s_waitcnt vmcnt(0)" ::: "memory");
    }
    asm volatile("" ::: "memory");
    __builtin_amdgcn_s_barrier();
    asm volatile("" ::: "memory");

    const unsigned ab = asb + (cur ? (unsigned)(BM * 128) : 0u);
    const unsigned bb = bsb + (cur ? (unsigned)(BN * 128) : 0u);
    // 4 K-steps of 16; grouped 2 per cluster
#pragma unroll
    for (int k2 = 0; k2 < 2; ++k2) {
      bf16x8 bfr[2][NT], af[2][MT];
#pragma unroll
      for (int kk = 0; kk < 2; ++kk) {
        const int ks = k2 * 2 + kk;
#pragma unroll
        for (int nt = 0; nt < NT; ++nt) {
          int row = wn + nt * 32 + cr;
          unsigned slot = (unsigned)(((ks * 2 + hg) ^ (row & 7) ^ ((row >> 3) & 3)) & 7);
          bfr[kk][nt] = ds128(bb + (unsigned)(row << 7) + (slot << 4));
        }
#pragma unroll
        for (int mt = 0; mt < MT; ++mt) {
          int row = wm + mt * 32 + cr;
          unsigned slot = (unsigned)(((ks * 2 + hg) ^ (row & 7) ^ ((row >> 3) & 3)) & 7);
          af[kk][mt] = ds128(ab + (unsigned)(row << 7) + (slot << 4));
        }
      }
      asm volatile("s_waitcnt lgkmcnt(0)" ::: "memory");
      __builtin_amdgcn_sched_barrier(0);
      __builtin_amdgcn_s_setprio(1);
#pragma unroll
      for (int kk = 0; kk < 2; ++kk)
#pragma unroll
        for (int mt = 0; mt < MT; ++mt)
#pragma unroll
          for (int nt = 0; nt < NT; ++nt)
            acc[mt][nt] = __builtin_amdgcn_mfma_f32_32x32x16_bf16(af[kk][mt], bfr[kk][nt],
                                                                  acc[mt][nt], 0, 0, 0);
      __builtin_amdgcn_s_setprio(0);
    }
    asm volatile("" ::: "memory");
    __builtin_amdgcn_s_barrier();
    asm volatile("" ::: "memory");
  }

  if (EPI == 1) {
    // fused proj + LN2 (BN == full row width 384)
#pragma unroll
    for (int mt = 0; mt < MT; ++mt) {
#pragma unroll
      for (int nt = 0; nt < NT; ++nt) {
        const int gn = nBase + wn + nt * 32 + cr;
#pragma unroll
        for (int r = 0; r < 16; ++r) {
          const int gm = mBase + wm + mt * 32 + (r & 3) + ((r >> 2) << 3) + (hg << 2);
          size_t idx = (size_t)gm * stride + gn;
          acc[mt][nt][r] = acc[mt][nt][r] + bias[gn] + residf[idx];
        }
      }
    }
    // row partials over this wave's col slice, reduce across the 32 col lanes
#pragma unroll
    for (int mt = 0; mt < MT; ++mt) {
#pragma unroll
      for (int r = 0; r < 16; ++r) {
        float s = 0.f, ss = 0.f;
#pragma unroll
        for (int nt = 0; nt < NT; ++nt) {
          float v = acc[mt][nt][r];
          s += v; ss += v * v;
        }
        s += __shfl_xor(s, 1);  ss += __shfl_xor(ss, 1);
        s += __shfl_xor(s, 2);  ss += __shfl_xor(ss, 2);
        s += __shfl_xor(s, 4);  ss += __shfl_xor(ss, 4);
        s += __shfl_xor(s, 8);  ss += __shfl_xor(ss, 8);
        s += __shfl_xor(s, 16); ss += __shfl_xor(ss, 16);
        if (cr == 0) {
          int row = wm + mt * 32 + (r & 3) + ((r >> 2) << 3) + (hg << 2);
          red[row][wni][0] = s;
          red[row][wni][1] = ss;
        }
      }
    }
    __syncthreads();
#pragma unroll
    for (int mt = 0; mt < MT; ++mt) {
#pragma unroll
      for (int r = 0; r < 16; ++r) {
        int row = wm + mt * 32 + (r & 3) + ((r >> 2) << 3) + (hg << 2);
        float s = red[row][0][0] + red[row][1][0] + red[row][2][0] + red[row][3][0];
        float ss = red[row][0][1] + red[row][1][1] + red[row][2][1] + red[row][3][1];
        float mu = s * (1.0f / 384.0f);
        float rstd = rsqrtf(ss * (1.0f / 384.0f) - mu * mu + 1e-5f);
        const int gm = mBase + row;
#pragma unroll
        for (int nt = 0; nt < NT; ++nt) {
          const int gn = nBase + wn + nt * 32 + cr;
          size_t idx = (size_t)gm * stride + gn;
          float x1v = acc[mt][nt][r];
          outb[idx] = f2bf(x1v);
          out2[idx] = f2bf((x1v - mu) * rstd * g2[gn] + be2[gn]);
        }
      }
    }
    return;
  }

#pragma unroll
  for (int mt = 0; mt < MT; ++mt) {
#pragma unroll
    for (int nt = 0; nt < NT; ++nt) {
      const int gn = nBase + wn + nt * 32 + cr;
      if (gn < Nst) {
#pragma unroll
        for (int r = 0; r < 16; ++r) {
          const int gm = mBase + wm + mt * 32 + (r & 3) + ((r >> 2) << 3) + (hg << 2);
          float val = acc[mt][nt][r];
          size_t idx = (size_t)gm * stride + gn;
          if (EPI == 0) {
            outb[idx] = f2bf(val);
          } else if (EPI == 2) {
            float rr = val + bias[gn];
            outb[idx] = f2bf(rr > 0.f ? rr : 0.f);
          } else {
            outf[idx] = val + bias[gn] + b2f(residb[idx]);
          }
        }
      }
    }
  }
}

__global__ __launch_bounds__(512, 1)
void gemm_qkv(const unsigned short* __restrict__ A, const unsigned short* __restrict__ Bt,
              int M, int K, int Nst, int stride, int ntx,
              const float* __restrict__ bias, const float* __restrict__ residf,
              const unsigned short* __restrict__ residb, float* __restrict__ outf,
              unsigned short* __restrict__ outb) {
  gemm_core<0, 256, 192, 4, 2>(A, Bt, M, K, Nst, stride, ntx, bias, residf, residb,
                               nullptr, nullptr, outf, outb, nullptr);
}
__global__ __launch_bounds__(512, 1)
void gemm_projln(const unsigned short* __restrict__ A, const unsigned short* __restrict__ Bt,
                 int M, int K, int Nst, int stride, int ntx,
                 const float* __restrict__ bias, const float* __restrict__ residf,
                 const float* __restrict__ g2, const float* __restrict__ be2,
                 unsigned short* __restrict__ outb, unsigned short* __restrict__ out2) {
  gemm_core<1, 128, 384, 2, 4>(A, Bt, M, K, Nst, stride, ntx, bias, residf, nullptr,
                               g2, be2, nullptr, outb, out2);
}
__global__ __launch_bounds__(512, 1)
void gemm_mlp1(const unsigned short* __restrict__ A, const unsigned short* __restrict__ Bt,
               int M, int K, int Nst, int stride, int ntx,
               const float* __restrict__ bias, const float* __restrict__ residf,
               const unsigned short* __restrict__ residb, float* __restrict__ outf,
               unsigned short* __restrict__ outb) {
  gemm_core<2, 256, 256, 2, 4>(A, Bt, M, K, Nst, stride, ntx, bias, residf, residb,
                               nullptr, nullptr, outf, outb, nullptr);
}
__global__ __launch_bounds__(512, 1)
void gemm_mlp2(const unsigned short* __restrict__ A, const unsigned short* __restrict__ Bt,
               int M, int K, int Nst, int stride, int ntx,
               const float* __restrict__ bias, const float* __restrict__ residf,
               const unsigned short* __restrict__ residb, float* __restrict__ outf,
               unsigned short* __restrict__ outb) {
  gemm_core<3, 128, 384, 2, 4>(A, Bt, M, K, Nst, stride, ntx, bias, residf, residb,
                               nullptr, nullptr, outf, outb, nullptr);
}

// ---------------- attention: one block per (b,h), 4 waves x 64 Q-rows ----------------
// Single pass: softmax without max-subtraction (S*scale small; guarded fminf 60).
__global__ __launch_bounds__(256)
void attn_kernel(const unsigned short* __restrict__ qkvn, unsigned short* __restrict__ o) {
  __shared__ unsigned short Vt[64 * 256];   // V^T [e][s], 16B-slot XOR swizzled
  __shared__ unsigned short Pw[4][64 * 32];
  const int bh = blockIdx.x;
  const int b = bh / 6, h = bh - b * 6;
  const unsigned short* base = qkvn + (size_t)(b * 256) * QSTR;
  const unsigned short* qb = base + h * 64;
  const unsigned short* kbp = base + 384 + h * 64;
  const unsigned short* vbp = base + 768 + h * 64;
  const int wave = threadIdx.x >> 6, lane = threadIdx.x & 63;
  const int fr = lane & 15, fg = lane >> 4;
  const int fk = fg << 3;
  const int qrow0 = wave << 6;
  const float scale = 0.051031036307982884f;  // 1/sqrt(384)
  const f32x4 z = {0.f, 0.f, 0.f, 0.f};

  {
    const int s = threadIdx.x;
    u16x8 v8[8];
#pragma unroll
    for (int j = 0; j < 8; ++j)
      v8[j] = *(const u16x8*)(vbp + (size_t)s * QSTR + j * 8);
#pragma unroll
    for (int e = 0; e < 64; ++e)
      Vt[(e << 8) + (s ^ ((e & 7) << 3))] = v8[e >> 3][e & 7];
  }
  __syncthreads();

  bf16x8 qf[4][2];
#pragma unroll
  for (int rb = 0; rb < 4; ++rb)
#pragma unroll
    for (int ks = 0; ks < 2; ++ks)
      qf[rb][ks] = *(const bf16x8*)(qb + (size_t)(qrow0 + rb * 16 + fr) * QSTR + ks * 32 + fk);

  f32x4 oacc[4][4];
  float psum[4][4];
#pragma unroll
  for (int rb = 0; rb < 4; ++rb)
#pragma unroll
    for (int nb = 0; nb < 4; ++nb) oacc[rb][nb] = z;
#pragma unroll
  for (int rb = 0; rb < 4; ++rb)
#pragma unroll
    for (int i = 0; i < 4; ++i) psum[rb][i] = 0.f;

  for (int kb2 = 0; kb2 < 8; ++kb2) {
#pragma unroll
    for (int c2 = 0; c2 < 2; ++c2) {
      int cb = kb2 * 2 + c2;
      bf16x8 kf0 = *(const bf16x8*)(kbp + (size_t)(cb * 16 + fr) * QSTR + fk);
      bf16x8 kf1 = *(const bf16x8*)(kbp + (size_t)(cb * 16 + fr) * QSTR + 32 + fk);
#pragma unroll
      for (int rb = 0; rb < 4; ++rb) {
        f32x4 s = __builtin_amdgcn_mfma_f32_16x16x32_bf16(qf[rb][0], kf0, z, 0, 0, 0);
        s = __builtin_amdgcn_mfma_f32_16x16x32_bf16(qf[rb][1], kf1, s, 0, 0, 0);
#pragma unroll
        for (int i = 0; i < 4; ++i) {
          float p = __expf(fminf(scale * s[i], 60.f));
          psum[rb][i] += p;
          Pw[wave][(rb * 16 + (fg << 2) + i) * 32 + c2 * 16 + fr] = f2bf(p);
        }
      }
    }
    bf16x8 pa[4], vf[4];
#pragma unroll
    for (int rb = 0; rb < 4; ++rb) pa[rb] = *(const bf16x8*)(&Pw[wave][(rb * 16 + fr) * 32 + fk]);
#pragma unroll
    for (int nb = 0; nb < 4; ++nb) {
      int e = nb * 16 + fr;
      vf[nb] = *(const bf16x8*)(&Vt[(e << 8) + ((kb2 * 32 + fk) ^ ((e & 7) << 3))]);
    }
#pragma unroll
    for (int rb = 0; rb < 4; ++rb)
#pragma unroll
      for (int nb = 0; nb < 4; ++nb)
        oacc[rb][nb] = __builtin_amdgcn_mfma_f32_16x16x32_bf16(pa[rb], vf[nb], oacc[rb][nb], 0, 0, 0);
  }

  float rs[4][4];
#pragma unroll
  for (int rb = 0; rb < 4; ++rb)
#pragma unroll
    for (int i = 0; i < 4; ++i) {
      float v = psum[rb][i];
      v += __shfl_xor(v, 1);
      v += __shfl_xor(v, 2);
      v += __shfl_xor(v, 4);
      v += __shfl_xor(v, 8);
      rs[rb][i] = 1.0f / v;
    }

#pragma unroll
  for (int rb = 0; rb < 4; ++rb)
#pragma unroll
    for (int nb = 0; nb < 4; ++nb)
#pragma unroll
      for (int i = 0; i < 4; ++i) {
        int token = b * 256 + qrow0 + rb * 16 + (fg << 2) + i;
        int gcol = h * 64 + nb * 16 + fr;
        o[(size_t)token * DE + gcol] = f2bf(oacc[rb][nb][i] * rs[rb][i]);
      }
}

// ---------------- launch ----------------
extern "C" void kernel_launch(void* const* d_in, const int* in_sizes, int n_in,
                              void* d_out, int out_size, void* d_ws, size_t ws_size,
                              hipStream_t stream) {
  const float* x     = (const float*)d_in[0];
  const float* wq    = (const float*)d_in[1];
  const float* wk    = (const float*)d_in[2];
  const float* wv    = (const float*)d_in[3];
  const float* wproj = (const float*)d_in[4];
  const float* bproj = (const float*)d_in[5];
  const float* w1    = (const float*)d_in[6];
  const float* b1    = (const float*)d_in[7];
  const float* w2    = (const float*)d_in[8];
  const float* b2    = (const float*)d_in[9];
  const float* g1    = (const float*)d_in[10];
  const float* be1   = (const float*)d_in[11];
  const float* g2    = (const float*)d_in[12];
  const float* be2   = (const float*)d_in[13];

  char* ws = (char*)d_ws;
  // lifetime-overlapped layout:
  //  xln  @0          (50MB, dead after qkv) ; x1b @0 (50MB bf16, projln out, live->mlp2)
  //  qkvn @50331648   (168MB, dead after attn)
  //  hbuf @100663296  (50MB, LN2 out from projln, inside dead qkvn)
  //  act  @150994944  (201MB, mlp1 out)
  //  attno@218103808  (50MB, dead after proj)
  //  weights @352321536
  unsigned short* xln   = (unsigned short*)(ws + 0);
  unsigned short* x1b   = (unsigned short*)(ws + 0);
  unsigned short* qkvn  = (unsigned short*)(ws + 50331648);
  unsigned short* hbuf  = (unsigned short*)(ws + 100663296);
  unsigned short* act   = (unsigned short*)(ws + 150994944);
  unsigned short* attno = (unsigned short*)(ws + 218103808);
  unsigned short* wqkvt = (unsigned short*)(ws + 352321536);                        // 983040 B
  unsigned short* wprjt = (unsigned short*)(ws + 352321536 + 983040);               // 294912 B
  unsigned short* w1t   = (unsigned short*)(ws + 352321536 + 983040 + 294912);      // 1179648 B
  unsigned short* w2t   = (unsigned short*)(ws + 352321536 + 983040 + 294912 + 1179648);

  pack_all<<<7104, 256, 0, stream>>>(wq, wk, wv, wproj, w1, w2,
                                     wqkvt, wprjt, w1t, w2t);

  ln_kernel<<<NTOK / 4, 256, 0, stream>>>(x, g1, be1, xln);

  // qkv: N computed = 1152 exactly (BN=192, ntx=6), storage stride 1280
  gemm_qkv<<<6 * 256, 512, 0, stream>>>(xln, wqkvt, NTOK, 384, 1152, 1280, 6,
                                        nullptr, nullptr, nullptr, nullptr, qkvn);

  attn_kernel<<<1536, 256, 0, stream>>>(qkvn, attno);

  // proj + LN2 fused: BM=128, BN=384 (full row per block), writes x1b + hbuf
  gemm_projln<<<512, 512, 0, stream>>>(attno, wprjt, NTOK, 384, 384, 384, 1,
                                       bproj, x, g2, be2, x1b, hbuf);

  gemm_mlp1<<<6 * 256, 512, 0, stream>>>(hbuf, w1t, NTOK, 384, 1536, 1536, 6,
                                         b1, nullptr, nullptr, nullptr, act);

  // mlp2: BM=128 x BN=384 (full row, ntx=1), wave-tile 64x96 (ratio 1.67)
  gemm_mlp2<<<512, 512, 0, stream>>>(act, w2t, NTOK, 1536, 384, 384, 1,
                                     b2, nullptr, x1b, (float*)d_out, nullptr);
}